// Round 1
// baseline (3827.113 us; speedup 1.0000x reference)
//
#include <hip/hip_runtime.h>
#include <math.h>

#define NB 64
#define NC 512
#define NT 128
#define NQ 8
#define NV 1024
#define NBIG 4194304      /* NB*NC*NT */
#define KW   1536         /* NC*3 */
#define IDX_STRIDE 255

/* ------------------------------------------------------------------ init */
__global__ void init_kernel(const float* __restrict__ z, float* __restrict__ z_q,
                            float* __restrict__ zhat, int* __restrict__ counts,
                            float* __restrict__ accums) {
    int i = blockIdx.x * 256 + threadIdx.x;
    const int stride = 2048 * 256;
    for (; i < NBIG; i += stride) {
        z_q[i]  = z[i];
        zhat[i] = 0.f;
        if (i < NQ * NV) counts[i] = 0;
        if (i < 16)      accums[i] = 0.f;
    }
}

/* --------------------------------------------------- codebook |c|^2 rows */
__global__ void cnorm_kernel(const float* __restrict__ cb, float* __restrict__ cnorm) {
    int wid  = (blockIdx.x * 256 + threadIdx.x) >> 6;   /* one wave per (q,v) row */
    int lane = threadIdx.x & 63;
    if (wid >= NQ * NV) return;
    const float* row = cb + (size_t)wid * NC;
    float s = 0.f;
    #pragma unroll
    for (int e = 0; e < NC / 64; ++e) { float v = row[lane + e * 64]; s = fmaf(v, v, s); }
    #pragma unroll
    for (int m = 32; m >= 1; m >>= 1) s += __shfl_xor(s, m, 64);
    if (lane == 0) cnorm[wid] = s;
}

/* ------------------------------------------- window-mean downsample->xdT */
/* xdT[r, c], r = b*s + j  (row-major, C=512 contiguous)                   */
__global__ void downsample_kernel(const float* __restrict__ z_q, float* __restrict__ xdT,
                                  int s, int log2s) {
    int r = blockIdx.x;
    int c = blockIdx.y * 256 + threadIdx.x;
    int b = r >> log2s;
    int j = r & (s - 1);
    int w = NT >> log2s;
    const float* src = z_q + ((size_t)(b * NC + c)) * NT + j * w;
    float sum = 0.f;
    for (int i = 0; i < w; ++i) sum += src[i];
    xdT[(size_t)r * NC + c] = sum * (1.f / (float)w);
}

/* --------------------------- distance GEMM + per-block argmin (64x64 tile) */
__global__ __launch_bounds__(256) void quant_gemm_kernel(
        const float* __restrict__ xdT, const float* __restrict__ cb,
        const float* __restrict__ cnorm, float* __restrict__ pval,
        int* __restrict__ pidx) {
    __shared__ float As[16][64];
    __shared__ float Bs[16][64];
    int vblk = blockIdx.x;          /* 0..15 */
    int rblk = blockIdx.y;
    int r0 = rblk * 64, v0 = vblk * 64;
    int tid = threadIdx.x;
    int tx = tid & 15, ty = tid >> 4;
    int lrow = tid >> 2, lc = (tid & 3) * 4;
    float acc[4][4] = {};
    for (int kk = 0; kk < NC; kk += 16) {
        float4 a = *(const float4*)(xdT + (size_t)(r0 + lrow) * NC + kk + lc);
        float4 b = *(const float4*)(cb  + (size_t)(v0 + lrow) * NC + kk + lc);
        __syncthreads();
        As[lc + 0][lrow] = a.x; As[lc + 1][lrow] = a.y; As[lc + 2][lrow] = a.z; As[lc + 3][lrow] = a.w;
        Bs[lc + 0][lrow] = b.x; Bs[lc + 1][lrow] = b.y; Bs[lc + 2][lrow] = b.z; Bs[lc + 3][lrow] = b.w;
        __syncthreads();
        #pragma unroll
        for (int k = 0; k < 16; ++k) {
            float av[4], bv[4];
            *(float4*)&av[0] = *(const float4*)&As[k][ty * 4];
            *(float4*)&bv[0] = *(const float4*)&Bs[k][tx * 4];
            #pragma unroll
            for (int im = 0; im < 4; ++im)
                #pragma unroll
                for (int iv = 0; iv < 4; ++iv)
                    acc[im][iv] = fmaf(av[im], bv[iv], acc[im][iv]);
        }
    }
    /* per-row argmin of (|c|^2 - 2 x.c) over this block's 64 codes */
    #pragma unroll
    for (int im = 0; im < 4; ++im) {
        float bv = 1e30f; int bi = 0;
        #pragma unroll
        for (int iv = 0; iv < 4; ++iv) {
            int v = v0 + tx * 4 + iv;
            float sc = cnorm[v] - 2.f * acc[im][iv];
            if (sc < bv) { bv = sc; bi = v; }
        }
        #pragma unroll
        for (int m = 1; m <= 8; m <<= 1) {
            float ov = __shfl_xor(bv, m, 64);
            int   oi = __shfl_xor(bi, m, 64);
            if (ov < bv || (ov == bv && oi < bi)) { bv = ov; bi = oi; }
        }
        if (tx == 0) {
            int r = r0 + ty * 4 + im;
            pval[(size_t)r * 16 + vblk] = bv;
            pidx[(size_t)r * 16 + vblk] = bi;
        }
    }
}

/* ------------------------------------- cross-block argmin + idx + counts */
__global__ void argmin_final_kernel(const float* __restrict__ pval, const int* __restrict__ pidx,
                                    int* __restrict__ idx_int, int* __restrict__ counts,
                                    float* __restrict__ out_idx, int R, int s, int log2s, int offq) {
    int r = blockIdx.x * 256 + threadIdx.x;
    if (r >= R) return;
    float bv = 1e30f; int bi = 0;
    #pragma unroll
    for (int k = 0; k < 16; ++k) {
        float v = pval[(size_t)r * 16 + k];
        int   i = pidx[(size_t)r * 16 + k];
        if (v < bv || (v == bv && i < bi)) { bv = v; bi = i; }
    }
    idx_int[r] = bi;
    atomicAdd(&counts[bi], 1);
    int b = r >> log2s, j = r & (s - 1);
    out_idx[(size_t)b * IDX_STRIDE + offq + j] = (float)bi;
}

/* -------------------------------- linear upsample (jax half-pixel conv.) */
__global__ void upsample_kernel(const float* __restrict__ cb, const int* __restrict__ idx_int,
                                float* __restrict__ up, int s, int log2s) {
    int bc = blockIdx.x;            /* b*512 + c */
    int b = bc >> 9;
    int c = bc & 511;
    int t = threadIdx.x;
    float in = (t + 0.5f) * ((float)s * (1.f / 128.f)) - 0.5f;
    float jf = floorf(in);
    float f = in - jf;
    int j0 = (int)jf;
    int i0 = min(max(j0, 0), s - 1);
    int i1 = min(max(j0 + 1, 0), s - 1);
    const int* ib = idx_int + b * s;
    float v0 = cb[(size_t)ib[i0] * NC + c];
    float v1 = cb[(size_t)ib[i1] * NC + c];
    up[(size_t)bc * NT + t] = (1.f - f) * v0 + f * v1;
}

/* ------------------- conv1d(K=3,'same') as im2col GEMM, 128x64 tile ----- */
/* MODE 0: out = relu(conv(X)+bias)                                        */
/* MODE 1: v = relu(conv(X)+bias); zhat += v; zq -= v                      */
template<int MODE>
__global__ __launch_bounds__(256) void conv_gemm_kernel(
        const float* __restrict__ X, const float* __restrict__ W,
        const float* __restrict__ bias, float* __restrict__ out,
        float* __restrict__ zhat, float* __restrict__ zq) {
    __shared__ float As[16][128];
    __shared__ float Bs[16][64];
    int nblk = blockIdx.x;          /* 0..127 : n-tile (b,t) */
    int mblk = blockIdx.y;          /* 0..3   : co-tile      */
    int m0 = mblk * 128;
    int n0 = nblk * 64;
    int b = n0 >> 7;
    int tbase = n0 & 127;
    int tid = threadIdx.x;
    int tx = tid & 15, ty = tid >> 4;
    /* A staging: thread -> row=tid>>1, 8 consecutive floats at (tid&1)*8 */
    int ar  = tid >> 1;
    int acb = (tid & 1) * 8;
    /* B staging: row=tid>>4 (k within tile), 4 floats at (tid&15)*4 */
    int brow = tid >> 4, bc4 = (tid & 15) * 4;
    float acc[8][4] = {};
    for (int kk = 0; kk < KW; kk += 16) {
        const float* wrow = W + (size_t)(m0 + ar) * KW + kk + acb;
        float4 a0 = *(const float4*)(wrow);
        float4 a1 = *(const float4*)(wrow + 4);
        int kidx = kk + brow;
        int ci = kidx / 3;
        int ks = kidx - ci * 3;
        const float* xrow = X + (size_t)(b * NC + ci) * NT;
        float bvals[4];
        #pragma unroll
        for (int e = 0; e < 4; ++e) {
            int tp = tbase + bc4 + e + ks - 1;
            bvals[e] = (tp >= 0 && tp < NT) ? xrow[tp] : 0.f;
        }
        __syncthreads();
        As[acb + 0][ar] = a0.x; As[acb + 1][ar] = a0.y; As[acb + 2][ar] = a0.z; As[acb + 3][ar] = a0.w;
        As[acb + 4][ar] = a1.x; As[acb + 5][ar] = a1.y; As[acb + 6][ar] = a1.z; As[acb + 7][ar] = a1.w;
        *(float4*)&Bs[brow][bc4] = make_float4(bvals[0], bvals[1], bvals[2], bvals[3]);
        __syncthreads();
        #pragma unroll
        for (int k = 0; k < 16; ++k) {
            float av[8], bv[4];
            *(float4*)&av[0] = *(const float4*)&As[k][ty * 8];
            *(float4*)&av[4] = *(const float4*)&As[k][ty * 8 + 4];
            *(float4*)&bv[0] = *(const float4*)&Bs[k][tx * 4];
            #pragma unroll
            for (int im = 0; im < 8; ++im)
                #pragma unroll
                for (int e = 0; e < 4; ++e)
                    acc[im][e] = fmaf(av[im], bv[e], acc[im][e]);
        }
    }
    #pragma unroll
    for (int im = 0; im < 8; ++im) {
        int m = m0 + ty * 8 + im;
        float bs = bias[m];
        #pragma unroll
        for (int e = 0; e < 4; ++e) {
            int t = tbase + tx * 4 + e;
            size_t oi = (size_t)(b * NC + m) * NT + t;
            float y = acc[im][e] + bs;
            y = y > 0.f ? y : 0.f;
            if (MODE == 0) {
                out[oi] = y;
            } else {
                zhat[oi] += y;
                zq[oi]   -= y;
            }
        }
    }
}

/* ---------------------------------------------- loss partial reduction  */
__global__ void loss_reduce_kernel(const float* __restrict__ zhat, const float* __restrict__ z,
                                   float* __restrict__ lpart) {
    __shared__ float sm[256];
    int tid = threadIdx.x;
    size_t i = (size_t)blockIdx.x * 256 + tid;
    float s = 0.f;
    for (; i < NBIG; i += (size_t)1024 * 256) {
        float d = zhat[i] - z[i];
        s = fmaf(d, d, s);
    }
    sm[tid] = s;
    __syncthreads();
    for (int st = 128; st >= 1; st >>= 1) {
        if (tid < st) sm[tid] += sm[tid + st];
        __syncthreads();
    }
    if (tid == 0) lpart[blockIdx.x] = sm[0];
}

/* --------------------- per-scale: finalize loss + usage + perplexity --- */
__global__ void scale_final_kernel(const float* __restrict__ lpart, const int* __restrict__ counts,
                                   float* __restrict__ accums, float invBS) {
    __shared__ float sm[256];
    __shared__ float se[256];
    __shared__ int   su[256];
    int tid = threadIdx.x;
    float ls = lpart[tid] + lpart[tid + 256] + lpart[tid + 512] + lpart[tid + 768];
    int used = 0; float ent = 0.f;
    #pragma unroll
    for (int k = 0; k < 4; ++k) {
        int cv = counts[tid + k * 256];
        if (cv > 0) used++;
        float p = (float)cv * invBS;
        ent = fmaf(p, logf(p + 1e-10f), ent);
    }
    sm[tid] = ls; se[tid] = ent; su[tid] = used;
    __syncthreads();
    for (int st = 128; st >= 1; st >>= 1) {
        if (tid < st) { sm[tid] += sm[tid + st]; se[tid] += se[tid + st]; su[tid] += su[tid + st]; }
        __syncthreads();
    }
    if (tid == 0) {
        float m = sm[0] * (1.f / (float)NBIG);
        accums[1] += 0.25f * m + m;                        /* (beta+1)*mse  */
        accums[0] += ((float)su[0] * (1.f / 1024.f)) * 100.f;
        accums[2] += expf(-se[0]);
    }
}

__global__ void final_write_kernel(const float* __restrict__ accums, float* __restrict__ outscal) {
    int t = threadIdx.x;
    if (t < 3) outscal[t] = accums[t] * 0.125f;            /* /= nQ */
}

/* ====================================================================== */
extern "C" void kernel_launch(void* const* d_in, const int* in_sizes, int n_in,
                              void* d_out, int out_size, void* d_ws, size_t ws_size,
                              hipStream_t stream) {
    const float* z  = (const float*)d_in[0];
    const float* cb = (const float*)d_in[1];
    const float* pw = (const float*)d_in[2];
    const float* pb = (const float*)d_in[3];

    float* zhat     = (float*)d_out;
    float* out_scal = zhat + NBIG;
    float* out_idx  = zhat + NBIG + 3;

    char* w = (char*)d_ws;
    float* z_q   = (float*)w;  w += (size_t)NBIG * 4;
    float* up    = (float*)w;  w += (size_t)NBIG * 4;
    float* h1    = (float*)w;  w += (size_t)NBIG * 4;
    float* xdT   = (float*)w;  w += (size_t)NBIG * 4;           /* max R=8192 x 512 */
    float* pval  = (float*)w;  w += (size_t)8192 * 16 * 4;
    int*   pidx  = (int*)w;    w += (size_t)8192 * 16 * 4;
    int*   idx_i = (int*)w;    w += (size_t)16384 * 4;
    int*   counts= (int*)w;    w += (size_t)NQ * NV * 4;
    float* cnorm = (float*)w;  w += (size_t)NQ * NV * 4;
    float* lpart = (float*)w;  w += (size_t)1024 * 4;
    float* accums= (float*)w;  w += 64;

    init_kernel<<<2048, 256, 0, stream>>>(z, z_q, zhat, counts, accums);
    cnorm_kernel<<<(NQ * NV) / 4, 256, 0, stream>>>(cb, cnorm);

    int offq = 0;
    for (int q = 0; q < NQ; ++q) {
        int s = 1 << q;
        int R = NB * s;
        const float* cbq = cb + (size_t)q * NV * NC;
        const float* wq0 = pw + (size_t)q * 2 * NC * KW;
        const float* wq1 = wq0 + (size_t)NC * KW;
        const float* bq0 = pb + (size_t)q * 2 * NC;
        const float* bq1 = bq0 + NC;

        downsample_kernel<<<dim3(R, 2), 256, 0, stream>>>(z_q, xdT, s, q);
        quant_gemm_kernel<<<dim3(16, R / 64), 256, 0, stream>>>(xdT, cbq, cnorm + q * NV, pval, pidx);
        argmin_final_kernel<<<(R + 255) / 256, 256, 0, stream>>>(pval, pidx, idx_i,
                                                                 counts + q * NV, out_idx, R, s, q, offq);
        upsample_kernel<<<NB * NC, 128, 0, stream>>>(cbq, idx_i, up, s, q);
        conv_gemm_kernel<0><<<dim3(128, 4), 256, 0, stream>>>(up, wq0, bq0, h1, nullptr, nullptr);
        conv_gemm_kernel<1><<<dim3(128, 4), 256, 0, stream>>>(h1, wq1, bq1, nullptr, zhat, z_q);
        loss_reduce_kernel<<<1024, 256, 0, stream>>>(zhat, z, lpart);
        scale_final_kernel<<<1, 256, 0, stream>>>(lpart, counts + q * NV, accums, 1.f / (float)(NB * s));
        offq += s;
    }
    final_write_kernel<<<1, 64, 0, stream>>>(accums, out_scal);
}

// Round 2
// 2576.196 us; speedup vs baseline: 1.4856x; 1.4856x over previous
//
#include <hip/hip_runtime.h>
#include <math.h>

#define NB 64
#define NC 512
#define NT 128
#define NQ 8
#define NV 1024
#define NBIG 4194304      /* NB*NC*NT */
#define KW   1536         /* NC*3 */
#define IDX_STRIDE 255

typedef __bf16 bf16x8 __attribute__((ext_vector_type(8)));
typedef float  f32x4  __attribute__((ext_vector_type(4)));

#define GLD16(g, l) __builtin_amdgcn_global_load_lds( \
    (const __attribute__((address_space(1))) unsigned int*)(g), \
    (__attribute__((address_space(3))) unsigned int*)(l), 16, 0, 0)

__device__ inline unsigned short bf16rne(float f, float& rem) {
    unsigned u = __float_as_uint(f);
    unsigned r = u + 0x7FFF + ((u >> 16) & 1);
    unsigned short h = (unsigned short)(r >> 16);
    rem = f - __uint_as_float((unsigned)h << 16);
    return h;
}

/* ------------------------------------------------------------------ init */
__global__ void init_kernel(const float* __restrict__ z, float* __restrict__ z_q,
                            float* __restrict__ zhat, int* __restrict__ counts,
                            float* __restrict__ accums) {
    int i = blockIdx.x * 256 + threadIdx.x;
    const int stride = 2048 * 256;
    for (; i < NBIG; i += stride) {
        z_q[i]  = z[i];
        zhat[i] = 0.f;
        if (i < NQ * NV) counts[i] = 0;
        if (i < 16)      accums[i] = 0.f;
    }
}

/* zero the pad rows (t=-1 and t=128) of the Xb split buffers, once */
__global__ void padzero_kernel(unsigned short* __restrict__ X1,
                               unsigned short* __restrict__ X2,
                               unsigned short* __restrict__ X3) {
    int b = blockIdx.x;
    int row = blockIdx.y ? 129 : 0;
    int c = threadIdx.x;
    size_t off = ((size_t)b * 130 + row) * NC + c;
    X1[off] = 0; X2[off] = 0; X3[off] = 0;
}

/* --------------------------------------------------- codebook |c|^2 rows */
__global__ void cnorm_kernel(const float* __restrict__ cb, float* __restrict__ cnorm) {
    int wid  = (blockIdx.x * 256 + threadIdx.x) >> 6;
    int lane = threadIdx.x & 63;
    if (wid >= NQ * NV) return;
    const float* row = cb + (size_t)wid * NC;
    float s = 0.f;
    #pragma unroll
    for (int e = 0; e < NC / 64; ++e) { float v = row[lane + e * 64]; s = fmaf(v, v, s); }
    #pragma unroll
    for (int m = 32; m >= 1; m >>= 1) s += __shfl_xor(s, m, 64);
    if (lane == 0) cnorm[wid] = s;
}

/* ------------------------------------------- window-mean downsample->xdT */
__global__ void downsample_kernel(const float* __restrict__ z_q, float* __restrict__ xdT,
                                  int s, int log2s) {
    int r = blockIdx.x;
    int c = blockIdx.y * 256 + threadIdx.x;
    int b = r >> log2s;
    int j = r & (s - 1);
    int w = NT >> log2s;
    const float* src = z_q + ((size_t)(b * NC + c)) * NT + j * w;
    float sum = 0.f;
    for (int i = 0; i < w; ++i) sum += src[i];
    xdT[(size_t)r * NC + c] = sum * (1.f / (float)w);
}

/* --------------------------- distance GEMM + per-block argmin (64x64 tile) */
__global__ __launch_bounds__(256) void quant_gemm_kernel(
        const float* __restrict__ xdT, const float* __restrict__ cb,
        const float* __restrict__ cnorm, float* __restrict__ pval,
        int* __restrict__ pidx) {
    __shared__ float As[16][64];
    __shared__ float Bs[16][64];
    int vblk = blockIdx.x;
    int rblk = blockIdx.y;
    int r0 = rblk * 64, v0 = vblk * 64;
    int tid = threadIdx.x;
    int tx = tid & 15, ty = tid >> 4;
    int lrow = tid >> 2, lc = (tid & 3) * 4;
    float acc[4][4] = {};
    for (int kk = 0; kk < NC; kk += 16) {
        float4 a = *(const float4*)(xdT + (size_t)(r0 + lrow) * NC + kk + lc);
        float4 b = *(const float4*)(cb  + (size_t)(v0 + lrow) * NC + kk + lc);
        __syncthreads();
        As[lc + 0][lrow] = a.x; As[lc + 1][lrow] = a.y; As[lc + 2][lrow] = a.z; As[lc + 3][lrow] = a.w;
        Bs[lc + 0][lrow] = b.x; Bs[lc + 1][lrow] = b.y; Bs[lc + 2][lrow] = b.z; Bs[lc + 3][lrow] = b.w;
        __syncthreads();
        #pragma unroll
        for (int k = 0; k < 16; ++k) {
            float av[4], bv[4];
            *(float4*)&av[0] = *(const float4*)&As[k][ty * 4];
            *(float4*)&bv[0] = *(const float4*)&Bs[k][tx * 4];
            #pragma unroll
            for (int im = 0; im < 4; ++im)
                #pragma unroll
                for (int iv = 0; iv < 4; ++iv)
                    acc[im][iv] = fmaf(av[im], bv[iv], acc[im][iv]);
        }
    }
    #pragma unroll
    for (int im = 0; im < 4; ++im) {
        float bv = 1e30f; int bi = 0;
        #pragma unroll
        for (int iv = 0; iv < 4; ++iv) {
            int v = v0 + tx * 4 + iv;
            float sc = cnorm[v] - 2.f * acc[im][iv];
            if (sc < bv) { bv = sc; bi = v; }
        }
        #pragma unroll
        for (int m = 1; m <= 8; m <<= 1) {
            float ov = __shfl_xor(bv, m, 64);
            int   oi = __shfl_xor(bi, m, 64);
            if (ov < bv || (ov == bv && oi < bi)) { bv = ov; bi = oi; }
        }
        if (tx == 0) {
            int r = r0 + ty * 4 + im;
            pval[(size_t)r * 16 + vblk] = bv;
            pidx[(size_t)r * 16 + vblk] = bi;
        }
    }
}

/* ------------------------------------- cross-block argmin + idx + counts */
__global__ void argmin_final_kernel(const float* __restrict__ pval, const int* __restrict__ pidx,
                                    int* __restrict__ idx_int, int* __restrict__ counts,
                                    float* __restrict__ out_idx, int R, int s, int log2s, int offq) {
    int r = blockIdx.x * 256 + threadIdx.x;
    if (r >= R) return;
    float bv = 1e30f; int bi = 0;
    #pragma unroll
    for (int k = 0; k < 16; ++k) {
        float v = pval[(size_t)r * 16 + k];
        int   i = pidx[(size_t)r * 16 + k];
        if (v < bv || (v == bv && i < bi)) { bv = v; bi = i; }
    }
    idx_int[r] = bi;
    atomicAdd(&counts[bi], 1);
    int b = r >> log2s, j = r & (s - 1);
    out_idx[(size_t)b * IDX_STRIDE + offq + j] = (float)bi;
}

/* ----------------- upsample + bf16 3-way split, padded Xt layout -------- */
/* X*[b][130][512]; row 0 and 129 are zero pads; row t+1 holds time t      */
__global__ void upsample_split_kernel(const float* __restrict__ cb, const int* __restrict__ idx_int,
                                      unsigned short* __restrict__ X1, unsigned short* __restrict__ X2,
                                      unsigned short* __restrict__ X3, int s, int log2s) {
    int b = blockIdx.x, tp = blockIdx.y, c = threadIdx.x;
    size_t off = ((size_t)b * 130 + tp) * NC + c;
    if (tp == 0 || tp == 129) { X1[off] = 0; X2[off] = 0; X3[off] = 0; return; }
    int t = tp - 1;
    float in = (t + 0.5f) * ((float)s * (1.f / 128.f)) - 0.5f;
    float jf = floorf(in);
    float f = in - jf;
    int j0 = (int)jf;
    int i0 = min(max(j0, 0), s - 1);
    int i1 = min(max(j0 + 1, 0), s - 1);
    const int* ib = idx_int + b * s;
    float v0 = cb[(size_t)ib[i0] * NC + c];
    float v1 = cb[(size_t)ib[i1] * NC + c];
    float v = (1.f - f) * v0 + f * v1;
    float r1, r2, r3;
    unsigned short h1 = bf16rne(v,  r1);
    unsigned short h2 = bf16rne(r1, r2);
    unsigned short h3 = bf16rne(r2, r3);
    X1[off] = h1; X2[off] = h2; X3[off] = h3;
}

/* ----- weight prep: split into 3 bf16 terms, tile+swizzle for the GEMM -- */
/* dest layout per conv: [term 3][mtile 4][ktile 24][8192] with element    */
/* (m,kk) at byte ((m*128 + kk*2) ^ ((m&7)<<4)); k = ks*512 + ci           */
__global__ void wprep_kernel(const float* __restrict__ W /* [2][512][512][3] */,
                             unsigned short* __restrict__ Wt /* 2 bufs */) {
    int d = blockIdx.y;
    const float* Wd = W + (size_t)d * NC * NC * 3;
    unsigned short* Wtd = Wt + (size_t)d * 3 * 4 * 24 * 8192;
    int idx = blockIdx.x * 256 + threadIdx.x;      /* 786432 = 4*24*8192 */
    int e  = idx & 8191;
    int rest = idx >> 13;
    int kt = rest % 24;
    int mt = rest / 24;
    int m = e >> 6, kk = e & 63;
    int k = kt * 64 + kk;
    int ks = k >> 9, ci = k & 511;
    int co = mt * 128 + m;
    float v = Wd[((size_t)co * NC + ci) * 3 + ks];
    float r1, r2, r3;
    unsigned short h1 = bf16rne(v,  r1);
    unsigned short h2 = bf16rne(r1, r2);
    unsigned short h3 = bf16rne(r2, r3);
    int off = ((m * 128 + kk * 2) ^ ((m & 7) << 4)) >> 1;
    size_t base = (((size_t)mt * 24) + kt) * 8192 + off;
    Wtd[base]               = h1;
    Wtd[base +   4*24*8192] = h2;
    Wtd[base + 2*4*24*8192] = h3;
}

/* --------------- bf16x3 MFMA conv GEMM: M=512, N=8192, K=6*1536 --------- */
/* MODE 0: y=relu(acc+bias) -> split -> Y1/2/3 (padded Xt layout)          */
/* MODE 1: y=relu(acc+bias); zhat+=y; zq-=y                                */
template<int MODE>
__global__ __launch_bounds__(256, 2) void conv_mfma_kernel(
        const unsigned short* __restrict__ Wt,
        const unsigned short* __restrict__ X1, const unsigned short* __restrict__ X2,
        const unsigned short* __restrict__ X3,
        const float* __restrict__ bias,
        unsigned short* __restrict__ Y1, unsigned short* __restrict__ Y2,
        unsigned short* __restrict__ Y3,
        float* __restrict__ zhat, float* __restrict__ zq) {
    __shared__ unsigned short As[8192];   /* 128m x 64k, swizzled, 16KB */
    __shared__ unsigned short Bs[4096];   /* 64n  x 64k, swizzled,  8KB */
    const int tid = threadIdx.x;
    const int w = tid >> 6, l = tid & 63;
    const int wm = w >> 1, wn = w & 1;            /* 2x2 waves -> 64m x 32n each */
    const int lane16 = l & 15, lhi = l >> 4;
    const int nblk = blockIdx.x, mt = blockIdx.y;
    const int b = nblk >> 1, t0 = (nblk & 1) << 6;
    f32x4 acc[4][2] = {};
    const int tA[6] = {0, 0, 1, 1, 0, 2};
    const int tX[6] = {0, 1, 0, 1, 2, 0};
    #pragma unroll
    for (int seg = 0; seg < 6; ++seg) {
        const unsigned short* Wb = Wt + ((size_t)(tA[seg] * 4 + mt)) * (24 * 8192);
        const unsigned short* Xu = (tX[seg] == 0) ? X1 : ((tX[seg] == 1) ? X2 : X3);
        for (int kt = 0; kt < 24; ++kt) {
            const int ks  = kt >> 3;
            const int ci0 = (kt & 7) << 6;
            __syncthreads();
            /* stage A (pre-tiled, pre-swizzled -> linear copy) */
            const char* wsrc = (const char*)(Wb + (size_t)kt * 8192);
            #pragma unroll
            for (int i = 0; i < 4; ++i)
                GLD16(wsrc + (i * 256 + tid) * 16, (char*)As + i * 4096 + w * 1024);
            /* stage B: row n from Xt[b][t0+n+ks][ci0..+63], source-chunk-swizzled */
            const int rowb = b * 130 + t0 + ks;
            #pragma unroll
            for (int i = 0; i < 2; ++i) {
                int c = i * 256 + tid;
                int n = c >> 3, sub = c & 7;
                const unsigned short* src = Xu + ((size_t)(rowb + n)) * NC + ci0 + ((sub ^ (n & 7)) << 3);
                GLD16(src, (char*)Bs + i * 4096 + w * 1024);
            }
            __syncthreads();
            #pragma unroll
            for (int kstep = 0; kstep < 2; ++kstep) {
                const int kb = (kstep * 32 + lhi * 8) * 2;
                bf16x8 af[4], bfr[2];
                #pragma unroll
                for (int im = 0; im < 4; ++im) {
                    int m = wm * 64 + im * 16 + lane16;
                    af[im] = *(const bf16x8*)((const char*)As + ((m * 128 + kb) ^ ((m & 7) << 4)));
                }
                #pragma unroll
                for (int in = 0; in < 2; ++in) {
                    int n = wn * 32 + in * 16 + lane16;
                    bfr[in] = *(const bf16x8*)((const char*)Bs + ((n * 128 + kb) ^ ((n & 7) << 4)));
                }
                #pragma unroll
                for (int im = 0; im < 4; ++im)
                    #pragma unroll
                    for (int in = 0; in < 2; ++in)
                        acc[im][in] = __builtin_amdgcn_mfma_f32_16x16x32_bf16(af[im], bfr[in], acc[im][in], 0, 0, 0);
            }
        }
    }
    /* epilogue: C/D layout col=lane&15 (n), row=lhi*4+reg (m) */
    #pragma unroll
    for (int im = 0; im < 4; ++im) {
        int mb = mt * 128 + wm * 64 + im * 16 + lhi * 4;
        float bs[4];
        #pragma unroll
        for (int r = 0; r < 4; ++r) bs[r] = bias[mb + r];
        #pragma unroll
        for (int in = 0; in < 2; ++in) {
            int t = t0 + wn * 32 + in * 16 + lane16;
            if (MODE == 0) {
                ushort4 h1v, h2v, h3v;
                unsigned short* p1 = (unsigned short*)&h1v;
                unsigned short* p2 = (unsigned short*)&h2v;
                unsigned short* p3 = (unsigned short*)&h3v;
                #pragma unroll
                for (int r = 0; r < 4; ++r) {
                    float y = acc[im][in][r] + bs[r];
                    y = y > 0.f ? y : 0.f;
                    float r1, r2, r3;
                    p1[r] = bf16rne(y,  r1);
                    p2[r] = bf16rne(r1, r2);
                    p3[r] = bf16rne(r2, r3);
                }
                size_t rowoff = ((size_t)(b * 130 + 1 + t)) * NC + mb;
                *(ushort4*)(Y1 + rowoff) = h1v;
                *(ushort4*)(Y2 + rowoff) = h2v;
                *(ushort4*)(Y3 + rowoff) = h3v;
            } else {
                size_t base = ((size_t)b * NC + mb) * NT + t;
                #pragma unroll
                for (int r = 0; r < 4; ++r) {
                    float y = acc[im][in][r] + bs[r];
                    y = y > 0.f ? y : 0.f;
                    size_t oi = base + (size_t)r * NT;
                    zhat[oi] += y;
                    zq[oi]   -= y;
                }
            }
        }
    }
}

/* ---------------- fallback fp32 conv path (round-1, known good) --------- */
__global__ void upsample_kernel(const float* __restrict__ cb, const int* __restrict__ idx_int,
                                float* __restrict__ up, int s, int log2s) {
    int bc = blockIdx.x;
    int b = bc >> 9;
    int c = bc & 511;
    int t = threadIdx.x;
    float in = (t + 0.5f) * ((float)s * (1.f / 128.f)) - 0.5f;
    float jf = floorf(in);
    float f = in - jf;
    int j0 = (int)jf;
    int i0 = min(max(j0, 0), s - 1);
    int i1 = min(max(j0 + 1, 0), s - 1);
    const int* ib = idx_int + b * s;
    float v0 = cb[(size_t)ib[i0] * NC + c];
    float v1 = cb[(size_t)ib[i1] * NC + c];
    up[(size_t)bc * NT + t] = (1.f - f) * v0 + f * v1;
}

template<int MODE>
__global__ __launch_bounds__(256) void conv_gemm_kernel(
        const float* __restrict__ X, const float* __restrict__ W,
        const float* __restrict__ bias, float* __restrict__ out,
        float* __restrict__ zhat, float* __restrict__ zq) {
    __shared__ float As[16][128];
    __shared__ float Bs[16][64];
    int nblk = blockIdx.x;
    int mblk = blockIdx.y;
    int m0 = mblk * 128;
    int n0 = nblk * 64;
    int b = n0 >> 7;
    int tbase = n0 & 127;
    int tid = threadIdx.x;
    int tx = tid & 15, ty = tid >> 4;
    int ar  = tid >> 1;
    int acb = (tid & 1) * 8;
    int brow = tid >> 4, bc4 = (tid & 15) * 4;
    float acc[8][4] = {};
    for (int kk = 0; kk < KW; kk += 16) {
        const float* wrow = W + (size_t)(m0 + ar) * KW + kk + acb;
        float4 a0 = *(const float4*)(wrow);
        float4 a1 = *(const float4*)(wrow + 4);
        int kidx = kk + brow;
        int ci = kidx / 3;
        int kss = kidx - ci * 3;
        const float* xrow = X + (size_t)(b * NC + ci) * NT;
        float bvals[4];
        #pragma unroll
        for (int e = 0; e < 4; ++e) {
            int tp = tbase + bc4 + e + kss - 1;
            bvals[e] = (tp >= 0 && tp < NT) ? xrow[tp] : 0.f;
        }
        __syncthreads();
        As[acb + 0][ar] = a0.x; As[acb + 1][ar] = a0.y; As[acb + 2][ar] = a0.z; As[acb + 3][ar] = a0.w;
        As[acb + 4][ar] = a1.x; As[acb + 5][ar] = a1.y; As[acb + 6][ar] = a1.z; As[acb + 7][ar] = a1.w;
        *(float4*)&Bs[brow][bc4] = make_float4(bvals[0], bvals[1], bvals[2], bvals[3]);
        __syncthreads();
        #pragma unroll
        for (int k = 0; k < 16; ++k) {
            float av[8], bv[4];
            *(float4*)&av[0] = *(const float4*)&As[k][ty * 8];
            *(float4*)&av[4] = *(const float4*)&As[k][ty * 8 + 4];
            *(float4*)&bv[0] = *(const float4*)&Bs[k][tx * 4];
            #pragma unroll
            for (int im = 0; im < 8; ++im)
                #pragma unroll
                for (int e = 0; e < 4; ++e)
                    acc[im][e] = fmaf(av[im], bv[e], acc[im][e]);
        }
    }
    #pragma unroll
    for (int im = 0; im < 8; ++im) {
        int m = m0 + ty * 8 + im;
        float bsv = bias[m];
        #pragma unroll
        for (int e = 0; e < 4; ++e) {
            int t = tbase + tx * 4 + e;
            size_t oi = (size_t)(b * NC + m) * NT + t;
            float y = acc[im][e] + bsv;
            y = y > 0.f ? y : 0.f;
            if (MODE == 0) {
                out[oi] = y;
            } else {
                zhat[oi] += y;
                zq[oi]   -= y;
            }
        }
    }
}

/* ---------------------------------------------- loss partial reduction  */
__global__ void loss_reduce_kernel(const float* __restrict__ zhat, const float* __restrict__ z,
                                   float* __restrict__ lpart) {
    __shared__ float sm[256];
    int tid = threadIdx.x;
    size_t i = (size_t)blockIdx.x * 256 + tid;
    float s = 0.f;
    for (; i < NBIG; i += (size_t)1024 * 256) {
        float d = zhat[i] - z[i];
        s = fmaf(d, d, s);
    }
    sm[tid] = s;
    __syncthreads();
    for (int st = 128; st >= 1; st >>= 1) {
        if (tid < st) sm[tid] += sm[tid + st];
        __syncthreads();
    }
    if (tid == 0) lpart[blockIdx.x] = sm[0];
}

/* --------------------- per-scale: finalize loss + usage + perplexity --- */
__global__ void scale_final_kernel(const float* __restrict__ lpart, const int* __restrict__ counts,
                                   float* __restrict__ accums, float invBS) {
    __shared__ float sm[256];
    __shared__ float se[256];
    __shared__ int   su[256];
    int tid = threadIdx.x;
    float ls = lpart[tid] + lpart[tid + 256] + lpart[tid + 512] + lpart[tid + 768];
    int used = 0; float ent = 0.f;
    #pragma unroll
    for (int k = 0; k < 4; ++k) {
        int cv = counts[tid + k * 256];
        if (cv > 0) used++;
        float p = (float)cv * invBS;
        ent = fmaf(p, logf(p + 1e-10f), ent);
    }
    sm[tid] = ls; se[tid] = ent; su[tid] = used;
    __syncthreads();
    for (int st = 128; st >= 1; st >>= 1) {
        if (tid < st) { sm[tid] += sm[tid + st]; se[tid] += se[tid + st]; su[tid] += su[tid + st]; }
        __syncthreads();
    }
    if (tid == 0) {
        float m = sm[0] * (1.f / (float)NBIG);
        accums[1] += 0.25f * m + m;
        accums[0] += ((float)su[0] * (1.f / 1024.f)) * 100.f;
        accums[2] += expf(-se[0]);
    }
}

__global__ void final_write_kernel(const float* __restrict__ accums, float* __restrict__ outscal) {
    int t = threadIdx.x;
    if (t < 3) outscal[t] = accums[t] * 0.125f;
}

/* ====================================================================== */
extern "C" void kernel_launch(void* const* d_in, const int* in_sizes, int n_in,
                              void* d_out, int out_size, void* d_ws, size_t ws_size,
                              hipStream_t stream) {
    const float* z  = (const float*)d_in[0];
    const float* cb = (const float*)d_in[1];
    const float* pw = (const float*)d_in[2];
    const float* pb = (const float*)d_in[3];

    float* zhat     = (float*)d_out;
    float* out_scal = zhat + NBIG;
    float* out_idx  = zhat + NBIG + 3;

    const size_t SZ_ZQ   = (size_t)NBIG * 4;
    const size_t SZ_XDT  = (size_t)8192 * 512 * 4;
    const size_t SZ_TERM = (size_t)64 * 130 * 512 * 2;     /* one bf16 split buffer */
    const size_t SZ_WT   = (size_t)3 * 4 * 24 * 8192 * 2;  /* one conv's W tiles    */
    const size_t SZ_SMALL = (size_t)524288 * 2 + 65536 + 32768 * 2 + 4096 + 256;
    const size_t need_new = SZ_ZQ + SZ_XDT + 6 * SZ_TERM + 2 * SZ_WT + SZ_SMALL + 4096;
    bool mfma_path = (ws_size >= need_new);

    if (mfma_path) {
        char* w = (char*)d_ws;
        float* z_q   = (float*)w;           w += SZ_ZQ;
        float* xdT   = (float*)w;           w += SZ_XDT;
        unsigned short* Xa1 = (unsigned short*)w; w += SZ_TERM;
        unsigned short* Xa2 = (unsigned short*)w; w += SZ_TERM;
        unsigned short* Xa3 = (unsigned short*)w; w += SZ_TERM;
        unsigned short* Xb1 = (unsigned short*)w; w += SZ_TERM;
        unsigned short* Xb2 = (unsigned short*)w; w += SZ_TERM;
        unsigned short* Xb3 = (unsigned short*)w; w += SZ_TERM;
        unsigned short* Wt  = (unsigned short*)w; w += 2 * SZ_WT;
        float* pval  = (float*)w;  w += (size_t)8192 * 16 * 4;
        int*   pidx  = (int*)w;    w += (size_t)8192 * 16 * 4;
        int*   idx_i = (int*)w;    w += (size_t)16384 * 4;
        int*   counts= (int*)w;    w += (size_t)NQ * NV * 4;
        float* cnorm = (float*)w;  w += (size_t)NQ * NV * 4;
        float* lpart = (float*)w;  w += (size_t)1024 * 4;
        float* accums= (float*)w;  w += 256;

        init_kernel<<<2048, 256, 0, stream>>>(z, z_q, zhat, counts, accums);
        padzero_kernel<<<dim3(64, 2), 512, 0, stream>>>(Xb1, Xb2, Xb3);
        cnorm_kernel<<<(NQ * NV) / 4, 256, 0, stream>>>(cb, cnorm);

        int offq = 0;
        for (int q = 0; q < NQ; ++q) {
            int s = 1 << q;
            int R = NB * s;
            const float* cbq = cb + (size_t)q * NV * NC;
            const float* wq  = pw + (size_t)q * 2 * NC * NC * 3;
            const float* bq0 = pb + (size_t)q * 2 * NC;
            const float* bq1 = bq0 + NC;

            downsample_kernel<<<dim3(R, 2), 256, 0, stream>>>(z_q, xdT, s, q);
            quant_gemm_kernel<<<dim3(16, R / 64), 256, 0, stream>>>(xdT, cbq, cnorm + q * NV, pval, pidx);
            argmin_final_kernel<<<(R + 255) / 256, 256, 0, stream>>>(pval, pidx, idx_i,
                                                                     counts + q * NV, out_idx, R, s, q, offq);
            upsample_split_kernel<<<dim3(64, 130), 512, 0, stream>>>(cbq, idx_i, Xa1, Xa2, Xa3, s, q);
            wprep_kernel<<<dim3(3072, 2), 256, 0, stream>>>(wq, Wt);
            conv_mfma_kernel<0><<<dim3(128, 4), 256, 0, stream>>>(
                Wt, Xa1, Xa2, Xa3, bq0, Xb1, Xb2, Xb3, nullptr, nullptr);
            conv_mfma_kernel<1><<<dim3(128, 4), 256, 0, stream>>>(
                Wt + SZ_WT / 2, Xb1, Xb2, Xb3, bq1, nullptr, nullptr, nullptr, zhat, z_q);
            loss_reduce_kernel<<<1024, 256, 0, stream>>>(zhat, z, lpart);
            scale_final_kernel<<<1, 256, 0, stream>>>(lpart, counts + q * NV, accums, 1.f / (float)(NB * s));
            offq += s;
        }
        final_write_kernel<<<1, 64, 0, stream>>>(accums, out_scal);
    } else {
        /* fallback: round-1 fp32 path */
        char* w = (char*)d_ws;
        float* z_q   = (float*)w;  w += (size_t)NBIG * 4;
        float* up    = (float*)w;  w += (size_t)NBIG * 4;
        float* h1    = (float*)w;  w += (size_t)NBIG * 4;
        float* xdT   = (float*)w;  w += (size_t)NBIG * 4;
        float* pval  = (float*)w;  w += (size_t)8192 * 16 * 4;
        int*   pidx  = (int*)w;    w += (size_t)8192 * 16 * 4;
        int*   idx_i = (int*)w;    w += (size_t)16384 * 4;
        int*   counts= (int*)w;    w += (size_t)NQ * NV * 4;
        float* cnorm = (float*)w;  w += (size_t)NQ * NV * 4;
        float* lpart = (float*)w;  w += (size_t)1024 * 4;
        float* accums= (float*)w;  w += 64;

        init_kernel<<<2048, 256, 0, stream>>>(z, z_q, zhat, counts, accums);
        cnorm_kernel<<<(NQ * NV) / 4, 256, 0, stream>>>(cb, cnorm);

        int offq = 0;
        for (int q = 0; q < NQ; ++q) {
            int s = 1 << q;
            int R = NB * s;
            const float* cbq = cb + (size_t)q * NV * NC;
            const float* wq0 = pw + (size_t)q * 2 * NC * KW;
            const float* wq1 = wq0 + (size_t)NC * KW;
            const float* bq0 = pb + (size_t)q * 2 * NC;
            const float* bq1 = bq0 + NC;

            downsample_kernel<<<dim3(R, 2), 256, 0, stream>>>(z_q, xdT, s, q);
            quant_gemm_kernel<<<dim3(16, R / 64), 256, 0, stream>>>(xdT, cbq, cnorm + q * NV, pval, pidx);
            argmin_final_kernel<<<(R + 255) / 256, 256, 0, stream>>>(pval, pidx, idx_i,
                                                                     counts + q * NV, out_idx, R, s, q, offq);
            upsample_kernel<<<NB * NC, 128, 0, stream>>>(cbq, idx_i, up, s, q);
            conv_gemm_kernel<0><<<dim3(128, 4), 256, 0, stream>>>(up, wq0, bq0, h1, nullptr, nullptr);
            conv_gemm_kernel<1><<<dim3(128, 4), 256, 0, stream>>>(h1, wq1, bq1, nullptr, zhat, z_q);
            loss_reduce_kernel<<<1024, 256, 0, stream>>>(zhat, z, lpart);
            scale_final_kernel<<<1, 256, 0, stream>>>(lpart, counts + q * NV, accums, 1.f / (float)(NB * s));
            offq += s;
        }
        final_write_kernel<<<1, 64, 0, stream>>>(accums, out_scal);
    }
}

// Round 3
// 1602.791 us; speedup vs baseline: 2.3878x; 1.6073x over previous
//
#include <hip/hip_runtime.h>
#include <math.h>

#define NB 64
#define NC 512
#define NT 128
#define NQ 8
#define NV 1024
#define NBIG 4194304      /* NB*NC*NT */
#define IDX_STRIDE 255

typedef _Float16 half_t;
typedef half_t f16x8 __attribute__((ext_vector_type(8)));
typedef float  f32x4 __attribute__((ext_vector_type(4)));

#define SC_MAIN 0.015625f           /* 2^-6  */
#define SC_MID  2.44140625e-4f      /* 2^-12 */

#define GLD16(g, l) __builtin_amdgcn_global_load_lds( \
    (const __attribute__((address_space(1))) unsigned int*)(g), \
    (__attribute__((address_space(3))) unsigned int*)(l), 16, 0, 0)

/* A-side split: W1 = fp16(64v), W2 = fp16((64v - W1)*64)  -> v = W1/64 + W2/4096 + O(2^-24 v) */
__device__ inline void split64(float v, half_t& h1, half_t& h2) {
    half_t a = (half_t)(v * 64.f);
    float r = v * 64.f - (float)a;
    h1 = a;
    h2 = (half_t)(r * 64.f);
}
/* X-side split: X1 = fp16(v), X2 = fp16((v - X1)*64)      -> v = X1 + X2/64 + O(2^-24 v) */
__device__ inline void split1(float v, half_t& h1, half_t& h2) {
    half_t a = (half_t)v;
    float r = v - (float)a;
    h1 = a;
    h2 = (half_t)(r * 64.f);
}

/* ------------------------------------------------------------------ init */
__global__ void init_kernel(float* __restrict__ zhat, int* __restrict__ counts,
                            float* __restrict__ accums) {
    int i = blockIdx.x * 256 + threadIdx.x;
    const int stride = 2048 * 256;
    for (; i < NBIG; i += stride) {
        zhat[i] = 0.f;
        if (i < NQ * NV) counts[i] = 0;
        if (i < 16)      accums[i] = 0.f;
    }
}

/* zero pad rows (t=-1 and t=128) of the Xb (hidden) buffers, once per call */
__global__ void padzero_kernel(half_t* __restrict__ X1, half_t* __restrict__ X2) {
    int b = blockIdx.x;
    int row = blockIdx.y ? 129 : 0;
    int c = threadIdx.x;
    size_t off = ((size_t)b * 130 + row) * NC + c;
    X1[off] = (half_t)0.f; X2[off] = (half_t)0.f;
}

/* --------------------------------------------------- codebook |c|^2 rows */
__global__ void cnorm_kernel(const float* __restrict__ cb, float* __restrict__ cnorm) {
    int wid  = (blockIdx.x * 256 + threadIdx.x) >> 6;
    int lane = threadIdx.x & 63;
    if (wid >= NQ * NV) return;
    const float* row = cb + (size_t)wid * NC;
    float s = 0.f;
    #pragma unroll
    for (int e = 0; e < NC / 64; ++e) { float v = row[lane + e * 64]; s = fmaf(v, v, s); }
    #pragma unroll
    for (int m = 32; m >= 1; m >>= 1) s += __shfl_xor(s, m, 64);
    if (lane == 0) cnorm[wid] = s;
}

/* ------ codebook prep: fp16 2-way split, tiled+swizzled for the GEMM ---- */
/* CbT layout: [q][term 2][mt 8][kt 8][8192], elem (m,kk) at short-off     */
/* (((m*128 + kk*2) ^ ((m&7)<<4)) >> 1); k = ci = kt*64+kk                 */
__global__ void cbprep_kernel(const float* __restrict__ cb, half_t* __restrict__ CbT) {
    int idx = blockIdx.x * 256 + threadIdx.x;     /* 8*8*8*8192 = 4194304 */
    int e  = idx & 8191;
    int kt = (idx >> 13) & 7;
    int mt = (idx >> 16) & 7;
    int q  = idx >> 19;
    int m = e >> 6, kk = e & 63;
    int ci = kt * 64 + kk;
    int code = mt * 128 + m;
    float v = cb[((size_t)(q * NV + code)) * NC + ci];
    half_t h1, h2;
    split64(v, h1, h2);
    int off = ((m * 128 + kk * 2) ^ ((m & 7) << 4)) >> 1;
    size_t base = ((((size_t)q * 2 + 0) * 8 + mt) * 8 + kt) * 8192 + off;
    CbT[base] = h1;
    CbT[base + (size_t)8 * 8 * 8192] = h2;        /* term stride within q */
}

/* ------------- window-mean downsample of (z - zhat) -> fp16 split ------ */
__global__ void downsample_split_kernel(const float* __restrict__ z, const float* __restrict__ zhat,
                                        half_t* __restrict__ Xd1, half_t* __restrict__ Xd2,
                                        int s, int log2s) {
    int r = blockIdx.x;
    int c = blockIdx.y * 256 + threadIdx.x;
    int b = r >> log2s;
    int j = r & (s - 1);
    int w = NT >> log2s;
    size_t base = ((size_t)(b * NC + c)) * NT + j * w;
    float sum = 0.f;
    for (int i = 0; i < w; ++i) sum += z[base + i] - zhat[base + i];
    float xd = sum * (1.f / (float)w);
    half_t h1, h2;
    split1(xd, h1, h2);
    Xd1[(size_t)r * NC + c] = h1;
    Xd2[(size_t)r * NC + c] = h2;
}

/* ---- quant: fp16x2 MFMA distance GEMM + fused per-block argmin --------- */
/* grid (R/64, 8mt), 256 thr. A = codebook tile (128 codes x 64k),         */
/* B = xd rows (64 x 64k). dist = cnorm - 2*(accM/64 + accm/4096)          */
__global__ __launch_bounds__(256, 2) void quant_mfma_kernel(
        const half_t* __restrict__ CbTq,
        const half_t* __restrict__ Xd1, const half_t* __restrict__ Xd2,
        const float* __restrict__ cnorm,
        float* __restrict__ pval, int* __restrict__ pidx) {
    __shared__ half_t As1[8192];
    __shared__ half_t As2[8192];
    __shared__ half_t Bs1[4096];
    __shared__ half_t Bs2[4096];
    __shared__ float redv[2][2][2][16];
    __shared__ int   redi[2][2][2][16];
    const int tid = threadIdx.x;
    const int w = tid >> 6, l = tid & 63;
    const int wm = w >> 1, wn = w & 1;
    const int lane16 = l & 15, lhi = l >> 4;
    const int nblk = blockIdx.x, mt = blockIdx.y;
    const int r0 = nblk * 64;
    f32x4 accM[4][2] = {}, accm[4][2] = {};
    const half_t* C1b = CbTq + ((size_t)(0 * 8 + mt)) * (8 * 8192);
    const half_t* C2b = CbTq + ((size_t)(1 * 8 + mt)) * (8 * 8192);
    for (int kt = 0; kt < 8; ++kt) {
        const int ci0 = kt << 6;
        __syncthreads();
        const char* c1src = (const char*)(C1b + (size_t)kt * 8192);
        const char* c2src = (const char*)(C2b + (size_t)kt * 8192);
        #pragma unroll
        for (int i = 0; i < 4; ++i) {
            GLD16(c1src + (i * 256 + tid) * 16, (char*)As1 + i * 4096 + w * 1024);
            GLD16(c2src + (i * 256 + tid) * 16, (char*)As2 + i * 4096 + w * 1024);
        }
        #pragma unroll
        for (int i = 0; i < 2; ++i) {
            int c = i * 256 + tid;
            int n = c >> 3, sub = c & 7;
            size_t soff = ((size_t)(r0 + n)) * NC + ci0 + ((sub ^ (n & 7)) << 3);
            GLD16(Xd1 + soff, (char*)Bs1 + i * 4096 + w * 1024);
            GLD16(Xd2 + soff, (char*)Bs2 + i * 4096 + w * 1024);
        }
        __syncthreads();
        #pragma unroll
        for (int kstep = 0; kstep < 2; ++kstep) {
            const int kb = (kstep * 32 + lhi * 8) * 2;
            f16x8 a1[4], a2[4], b1[2], b2[2];
            #pragma unroll
            for (int im = 0; im < 4; ++im) {
                int m = wm * 64 + im * 16 + lane16;
                int off = (m * 128 + kb) ^ ((m & 7) << 4);
                a1[im] = *(const f16x8*)((const char*)As1 + off);
                a2[im] = *(const f16x8*)((const char*)As2 + off);
            }
            #pragma unroll
            for (int in = 0; in < 2; ++in) {
                int n = wn * 32 + in * 16 + lane16;
                int off = (n * 128 + kb) ^ ((n & 7) << 4);
                b1[in] = *(const f16x8*)((const char*)Bs1 + off);
                b2[in] = *(const f16x8*)((const char*)Bs2 + off);
            }
            #pragma unroll
            for (int im = 0; im < 4; ++im)
                #pragma unroll
                for (int in = 0; in < 2; ++in) {
                    accM[im][in] = __builtin_amdgcn_mfma_f32_16x16x32_f16(a1[im], b1[in], accM[im][in], 0, 0, 0);
                    accm[im][in] = __builtin_amdgcn_mfma_f32_16x16x32_f16(a1[im], b2[in], accm[im][in], 0, 0, 0);
                    accm[im][in] = __builtin_amdgcn_mfma_f32_16x16x32_f16(a2[im], b1[in], accm[im][in], 0, 0, 0);
                }
        }
    }
    /* fused argmin: per-lane over 16 codes (ascending), xor-shuffle over lhi,
       cross-wave(wm) via LDS. first-min tie-break = lowest code index. */
    float bv[2] = {1e30f, 1e30f};
    int   bi[2] = {0, 0};
    #pragma unroll
    for (int im = 0; im < 4; ++im) {
        int mb = mt * 128 + wm * 64 + im * 16 + lhi * 4;
        float4 cn = *(const float4*)(cnorm + mb);
        const float* cnp = (const float*)&cn;
        #pragma unroll
        for (int in = 0; in < 2; ++in) {
            #pragma unroll
            for (int r = 0; r < 4; ++r) {
                float d = cnp[r] - 2.f * (accM[im][in][r] * SC_MAIN + accm[im][in][r] * SC_MID);
                int code = mb + r;
                if (d < bv[in]) { bv[in] = d; bi[in] = code; }
            }
        }
    }
    #pragma unroll
    for (int m = 16; m <= 32; m <<= 1) {
        #pragma unroll
        for (int in = 0; in < 2; ++in) {
            float ov = __shfl_xor(bv[in], m, 64);
            int   oi = __shfl_xor(bi[in], m, 64);
            if (ov < bv[in] || (ov == bv[in] && oi < bi[in])) { bv[in] = ov; bi[in] = oi; }
        }
    }
    if (lhi == 0) {
        #pragma unroll
        for (int in = 0; in < 2; ++in) { redv[wm][wn][in][lane16] = bv[in]; redi[wm][wn][in][lane16] = bi[in]; }
    }
    __syncthreads();
    if (wm == 0 && lhi == 0) {
        #pragma unroll
        for (int in = 0; in < 2; ++in) {
            float v0 = redv[0][wn][in][lane16]; int i0 = redi[0][wn][in][lane16];
            float v1 = redv[1][wn][in][lane16]; int i1 = redi[1][wn][in][lane16];
            if (v1 < v0 || (v1 == v0 && i1 < i0)) { v0 = v1; i0 = i1; }
            int r = r0 + wn * 32 + in * 16 + lane16;
            pval[(size_t)r * 8 + mt] = v0;
            pidx[(size_t)r * 8 + mt] = i0;
        }
    }
}

/* ------------------------------------- cross-block argmin + idx + counts */
__global__ void argmin_final_kernel(const float* __restrict__ pval, const int* __restrict__ pidx,
                                    int* __restrict__ idx_int, int* __restrict__ counts,
                                    float* __restrict__ out_idx, int R, int s, int log2s, int offq) {
    int r = blockIdx.x * 256 + threadIdx.x;
    if (r >= R) return;
    float bv = 1e30f; int bi = 0;
    #pragma unroll
    for (int k = 0; k < 8; ++k) {
        float v = pval[(size_t)r * 8 + k];
        int   i = pidx[(size_t)r * 8 + k];
        if (v < bv || (v == bv && i < bi)) { bv = v; bi = i; }
    }
    idx_int[r] = bi;
    atomicAdd(&counts[bi], 1);
    int b = r >> log2s, j = r & (s - 1);
    out_idx[(size_t)b * IDX_STRIDE + offq + j] = (float)bi;
}

/* ----------------- upsample + fp16 split, padded Xt layout -------------- */
/* X*[b][130][512]; rows 0,129 zero pads; row t+1 holds time t             */
__global__ void upsample_split_kernel(const float* __restrict__ cb, const int* __restrict__ idx_int,
                                      half_t* __restrict__ X1, half_t* __restrict__ X2, int s) {
    int b = blockIdx.x, tp = blockIdx.y, c = threadIdx.x;
    size_t off = ((size_t)b * 130 + tp) * NC + c;
    if (tp == 0 || tp == 129) { X1[off] = (half_t)0.f; X2[off] = (half_t)0.f; return; }
    int t = tp - 1;
    float in = (t + 0.5f) * ((float)s * (1.f / 128.f)) - 0.5f;
    float jf = floorf(in);
    float f = in - jf;
    int j0 = (int)jf;
    int i0 = min(max(j0, 0), s - 1);
    int i1 = min(max(j0 + 1, 0), s - 1);
    const int* ib = idx_int + b * s;
    float v0 = cb[(size_t)ib[i0] * NC + c];
    float v1 = cb[(size_t)ib[i1] * NC + c];
    float v = (1.f - f) * v0 + f * v1;
    half_t h1, h2;
    split1(v, h1, h2);
    X1[off] = h1; X2[off] = h2;
}

/* ----- weight prep: fp16 2-way split, tile+swizzle for the conv GEMM ---- */
/* Wt per conv: [term 2][mt 4][kt 24][8192]; k = ks*512 + ci               */
__global__ void wprep_kernel(const float* __restrict__ W /* [2][512][512][3] */,
                             half_t* __restrict__ Wt) {
    int d = blockIdx.y;
    const float* Wd = W + (size_t)d * NC * NC * 3;
    half_t* Wtd = Wt + (size_t)d * (2 * 4 * 24 * 8192);
    int idx = blockIdx.x * 256 + threadIdx.x;      /* 786432 = 4*24*8192 */
    int e  = idx & 8191;
    int rest = idx >> 13;
    int kt = rest % 24;
    int mtl = rest / 24;
    int m = e >> 6, kk = e & 63;
    int k = kt * 64 + kk;
    int ks = k >> 9, ci = k & 511;
    int co = mtl * 128 + m;
    float v = Wd[((size_t)co * NC + ci) * 3 + ks];
    half_t h1, h2;
    split64(v, h1, h2);
    int off = ((m * 128 + kk * 2) ^ ((m & 7) << 4)) >> 1;
    size_t base = ((size_t)mtl * 24 + kt) * 8192 + off;
    Wtd[base] = h1;
    Wtd[base + (size_t)4 * 24 * 8192] = h2;
}

/* -------- conv1d as fp16x2 MFMA GEMM, kt-major dual-term staging -------- */
/* MODE 0: y=relu(...); split -> Y1/Y2 (padded layout)                      */
/* MODE 1: y=relu(...); zhat+=y; fused loss partial sum -> lpart[block]     */
template<int MODE>
__global__ __launch_bounds__(256, 2) void conv_mfma_kernel(
        const half_t* __restrict__ Wt,
        const half_t* __restrict__ X1, const half_t* __restrict__ X2,
        const float* __restrict__ bias,
        half_t* __restrict__ Y1, half_t* __restrict__ Y2,
        float* __restrict__ zhat, const float* __restrict__ z,
        float* __restrict__ lpart) {
    __shared__ half_t As1[8192];
    __shared__ half_t As2[8192];
    __shared__ half_t Bs1[4096];
    __shared__ half_t Bs2[4096];
    const int tid = threadIdx.x;
    const int w = tid >> 6, l = tid & 63;
    const int wm = w >> 1, wn = w & 1;
    const int lane16 = l & 15, lhi = l >> 4;
    const int nblk = blockIdx.x, mt = blockIdx.y;
    const int b = nblk >> 1, t0 = (nblk & 1) << 6;
    f32x4 accM[4][2] = {}, accm[4][2] = {};
    const half_t* W1b = Wt + ((size_t)(0 * 4 + mt)) * (24 * 8192);
    const half_t* W2b = Wt + ((size_t)(1 * 4 + mt)) * (24 * 8192);
    for (int kt = 0; kt < 24; ++kt) {
        const int ks  = kt >> 3;
        const int ci0 = (kt & 7) << 6;
        const int rowb = b * 130 + t0 + ks;
        __syncthreads();
        const char* w1src = (const char*)(W1b + (size_t)kt * 8192);
        const char* w2src = (const char*)(W2b + (size_t)kt * 8192);
        #pragma unroll
        for (int i = 0; i < 4; ++i) {
            GLD16(w1src + (i * 256 + tid) * 16, (char*)As1 + i * 4096 + w * 1024);
            GLD16(w2src + (i * 256 + tid) * 16, (char*)As2 + i * 4096 + w * 1024);
        }
        #pragma unroll
        for (int i = 0; i < 2; ++i) {
            int c = i * 256 + tid;
            int n = c >> 3, sub = c & 7;
            size_t soff = ((size_t)(rowb + n)) * NC + ci0 + ((sub ^ (n & 7)) << 3);
            GLD16(X1 + soff, (char*)Bs1 + i * 4096 + w * 1024);
            GLD16(X2 + soff, (char*)Bs2 + i * 4096 + w * 1024);
        }
        __syncthreads();
        #pragma unroll
        for (int kstep = 0; kstep < 2; ++kstep) {
            const int kb = (kstep * 32 + lhi * 8) * 2;
            f16x8 a1[4], a2[4], b1[2], b2[2];
            #pragma unroll
            for (int im = 0; im < 4; ++im) {
                int m = wm * 64 + im * 16 + lane16;
                int off = (m * 128 + kb) ^ ((m & 7) << 4);
                a1[im] = *(const f16x8*)((const char*)As1 + off);
                a2[im] = *(const f16x8*)((const char*)As2 + off);
            }
            #pragma unroll
            for (int in = 0; in < 2; ++in) {
                int n = wn * 32 + in * 16 + lane16;
                int off = (n * 128 + kb) ^ ((n & 7) << 4);
                b1[in] = *(const f16x8*)((const char*)Bs1 + off);
                b2[in] = *(const f16x8*)((const char*)Bs2 + off);
            }
            #pragma unroll
            for (int im = 0; im < 4; ++im)
                #pragma unroll
                for (int in = 0; in < 2; ++in) {
                    accM[im][in] = __builtin_amdgcn_mfma_f32_16x16x32_f16(a1[im], b1[in], accM[im][in], 0, 0, 0);
                    accm[im][in] = __builtin_amdgcn_mfma_f32_16x16x32_f16(a1[im], b2[in], accm[im][in], 0, 0, 0);
                    accm[im][in] = __builtin_amdgcn_mfma_f32_16x16x32_f16(a2[im], b1[in], accm[im][in], 0, 0, 0);
                }
        }
    }
    /* epilogue: C/D layout col=lane&15 (n), row=lhi*4+reg (m) */
    float lsum = 0.f;
    #pragma unroll
    for (int im = 0; im < 4; ++im) {
        int mb = mt * 128 + wm * 64 + im * 16 + lhi * 4;
        float bs[4];
        #pragma unroll
        for (int r = 0; r < 4; ++r) bs[r] = bias[mb + r];
        #pragma unroll
        for (int in = 0; in < 2; ++in) {
            int t = t0 + wn * 32 + in * 16 + lane16;
            if (MODE == 0) {
                half_t h1v[4], h2v[4];
                #pragma unroll
                for (int r = 0; r < 4; ++r) {
                    float y = accM[im][in][r] * SC_MAIN + accm[im][in][r] * SC_MID + bs[r];
                    y = y > 0.f ? y : 0.f;
                    split1(y, h1v[r], h2v[r]);
                }
                size_t rowoff = ((size_t)(b * 130 + 1 + t)) * NC + mb;
                *(ushort4*)(Y1 + rowoff) = *(const ushort4*)h1v;
                *(ushort4*)(Y2 + rowoff) = *(const ushort4*)h2v;
            } else {
                size_t base = ((size_t)b * NC + mb) * NT + t;
                #pragma unroll
                for (int r = 0; r < 4; ++r) {
                    float y = accM[im][in][r] * SC_MAIN + accm[im][in][r] * SC_MID + bs[r];
                    y = y > 0.f ? y : 0.f;
                    size_t oi = base + (size_t)r * NT;
                    float zn = zhat[oi] + y;
                    zhat[oi] = zn;
                    float d = zn - z[oi];
                    lsum = fmaf(d, d, lsum);
                }
            }
        }
    }
    if (MODE == 1) {
        __syncthreads();
        float* red = (float*)As1;
        red[tid] = lsum;
        __syncthreads();
        for (int st = 128; st >= 1; st >>= 1) {
            if (tid < st) red[tid] += red[tid + st];
            __syncthreads();
        }
        if (tid == 0) lpart[blockIdx.y * 128 + blockIdx.x] = red[0];
    }
}

/* --------------------- per-scale: finalize loss + usage + perplexity --- */
__global__ void scale_final_kernel(const float* __restrict__ lpart, const int* __restrict__ counts,
                                   float* __restrict__ accums, float invBS) {
    __shared__ float sm[256];
    __shared__ float se[256];
    __shared__ int   su[256];
    int tid = threadIdx.x;
    float ls = lpart[tid] + lpart[tid + 256];
    int used = 0; float ent = 0.f;
    #pragma unroll
    for (int k = 0; k < 4; ++k) {
        int cv = counts[tid + k * 256];
        if (cv > 0) used++;
        float p = (float)cv * invBS;
        ent = fmaf(p, logf(p + 1e-10f), ent);
    }
    sm[tid] = ls; se[tid] = ent; su[tid] = used;
    __syncthreads();
    for (int st = 128; st >= 1; st >>= 1) {
        if (tid < st) { sm[tid] += sm[tid + st]; se[tid] += se[tid + st]; su[tid] += su[tid + st]; }
        __syncthreads();
    }
    if (tid == 0) {
        float m = sm[0] * (1.f / (float)NBIG);
        accums[1] += 0.25f * m + m;                        /* (beta+1)*mse  */
        accums[0] += ((float)su[0] * (1.f / 1024.f)) * 100.f;
        accums[2] += expf(-se[0]);
    }
}

__global__ void final_write_kernel(const float* __restrict__ accums, float* __restrict__ outscal) {
    int t = threadIdx.x;
    if (t < 3) outscal[t] = accums[t] * 0.125f;            /* /= nQ */
}

/* ====================================================================== */
extern "C" void kernel_launch(void* const* d_in, const int* in_sizes, int n_in,
                              void* d_out, int out_size, void* d_ws, size_t ws_size,
                              hipStream_t stream) {
    const float* z  = (const float*)d_in[0];
    const float* cb = (const float*)d_in[1];
    const float* pw = (const float*)d_in[2];
    const float* pb = (const float*)d_in[3];

    float* zhat     = (float*)d_out;
    float* out_scal = zhat + NBIG;
    float* out_idx  = zhat + NBIG + 3;

    char* w = (char*)d_ws;
    half_t* Xd1 = (half_t*)w;  w += (size_t)8192 * NC * 2;
    half_t* Xd2 = (half_t*)w;  w += (size_t)8192 * NC * 2;
    half_t* Xa1 = (half_t*)w;  w += (size_t)NB * 130 * NC * 2;
    half_t* Xa2 = (half_t*)w;  w += (size_t)NB * 130 * NC * 2;
    half_t* Xb1 = (half_t*)w;  w += (size_t)NB * 130 * NC * 2;
    half_t* Xb2 = (half_t*)w;  w += (size_t)NB * 130 * NC * 2;
    half_t* Wt  = (half_t*)w;  w += (size_t)2 * 2 * 4 * 24 * 8192 * 2;   /* 2 convs */
    half_t* CbT = (half_t*)w;  w += (size_t)NQ * 2 * 8 * 8 * 8192 * 2;
    float* pval  = (float*)w;  w += (size_t)8192 * 8 * 4;
    int*   pidx  = (int*)w;    w += (size_t)8192 * 8 * 4;
    int*   idx_i = (int*)w;    w += (size_t)16384 * 4;
    int*   counts= (int*)w;    w += (size_t)NQ * NV * 4;
    float* cnorm = (float*)w;  w += (size_t)NQ * NV * 4;
    float* lpart = (float*)w;  w += (size_t)512 * 4;
    float* accums= (float*)w;  w += 256;

    init_kernel<<<2048, 256, 0, stream>>>(zhat, counts, accums);
    padzero_kernel<<<dim3(64, 2), 512, 0, stream>>>(Xb1, Xb2);
    cnorm_kernel<<<(NQ * NV) / 4, 256, 0, stream>>>(cb, cnorm);
    cbprep_kernel<<<16384, 256, 0, stream>>>(cb, CbT);

    const size_t WT_CONV = (size_t)2 * 4 * 24 * 8192;   /* halves per conv */
    int offq = 0;
    for (int q = 0; q < NQ; ++q) {
        int s = 1 << q;
        int R = NB * s;
        const float* cbq = cb + (size_t)q * NV * NC;
        const float* wq  = pw + (size_t)q * 2 * NC * NC * 3;
        const float* bq0 = pb + (size_t)q * 2 * NC;
        const float* bq1 = bq0 + NC;

        downsample_split_kernel<<<dim3(R, 2), 256, 0, stream>>>(z, zhat, Xd1, Xd2, s, q);
        quant_mfma_kernel<<<dim3(R / 64, 8), 256, 0, stream>>>(
            CbT + (size_t)q * 2 * 8 * 8 * 8192, Xd1, Xd2, cnorm + q * NV, pval, pidx);
        argmin_final_kernel<<<(R + 255) / 256, 256, 0, stream>>>(pval, pidx, idx_i,
                                                                 counts + q * NV, out_idx, R, s, q, offq);
        upsample_split_kernel<<<dim3(64, 130), 512, 0, stream>>>(cbq, idx_i, Xa1, Xa2, s);
        wprep_kernel<<<dim3(3072, 2), 256, 0, stream>>>(wq, Wt);
        conv_mfma_kernel<0><<<dim3(128, 4), 256, 0, stream>>>(
            Wt, Xa1, Xa2, bq0, Xb1, Xb2, nullptr, nullptr, nullptr);
        conv_mfma_kernel<1><<<dim3(128, 4), 256, 0, stream>>>(
            Wt + WT_CONV, Xb1, Xb2, bq1, nullptr, nullptr, zhat, z, lpart);
        scale_final_kernel<<<1, 256, 0, stream>>>(lpart, counts + q * NV, accums, 1.f / (float)(NB * s));
        offq += s;
    }
    final_write_kernel<<<1, 64, 0, stream>>>(accums, out_scal);
}

// Round 4
// 1049.868 us; speedup vs baseline: 3.6453x; 1.5267x over previous
//
#include <hip/hip_runtime.h>
#include <math.h>

#define NB 64
#define NC 512
#define NT 128
#define NQ 8
#define NV 1024
#define NBIG 4194304      /* NB*NC*NT */
#define IDX_STRIDE 255

typedef _Float16 half_t;
typedef half_t f16x8 __attribute__((ext_vector_type(8)));
typedef float  f32x4 __attribute__((ext_vector_type(4)));

#define SC_MAIN 0.015625f           /* 2^-6  */
#define SC_MID  2.44140625e-4f      /* 2^-12 */

#define GLD16(g, l) __builtin_amdgcn_global_load_lds( \
    (const __attribute__((address_space(1))) unsigned int*)(g), \
    (__attribute__((address_space(3))) unsigned int*)(l), 16, 0, 0)

/* A-side split: W1 = fp16(64v), W2 = fp16((64v - W1)*64)  -> v = W1/64 + W2/4096 + O(2^-24 v) */
__device__ inline void split64(float v, half_t& h1, half_t& h2) {
    half_t a = (half_t)(v * 64.f);
    float r = v * 64.f - (float)a;
    h1 = a;
    h2 = (half_t)(r * 64.f);
}
/* X-side split: X1 = fp16(v), X2 = fp16((v - X1)*64)      -> v = X1 + X2/64 + O(2^-24 v) */
__device__ inline void split1(float v, half_t& h1, half_t& h2) {
    half_t a = (half_t)v;
    float r = v - (float)a;
    h1 = a;
    h2 = (half_t)(r * 64.f);
}

/* ------------------------------------------------------------------ init */
__global__ void init_kernel(float* __restrict__ zhat, int* __restrict__ counts,
                            float* __restrict__ accums) {
    int i = blockIdx.x * 256 + threadIdx.x;
    const int stride = 2048 * 256;
    for (; i < NBIG; i += stride) {
        zhat[i] = 0.f;
        if (i < NQ * NV) counts[i] = 0;
        if (i < 16)      accums[i] = 0.f;
    }
}

/* zero pad rows (t=-1 and t=128) of the Xb (hidden) buffers, once per call */
__global__ void padzero_kernel(half_t* __restrict__ X1, half_t* __restrict__ X2) {
    int b = blockIdx.x;
    int row = blockIdx.y ? 129 : 0;
    int c = threadIdx.x;
    size_t off = ((size_t)b * 130 + row) * NC + c;
    X1[off] = (half_t)0.f; X2[off] = (half_t)0.f;
}

/* --------------------------------------------------- codebook |c|^2 rows */
__global__ void cnorm_kernel(const float* __restrict__ cb, float* __restrict__ cnorm) {
    int wid  = (blockIdx.x * 256 + threadIdx.x) >> 6;
    int lane = threadIdx.x & 63;
    if (wid >= NQ * NV) return;
    const float* row = cb + (size_t)wid * NC;
    float s = 0.f;
    #pragma unroll
    for (int e = 0; e < NC / 64; ++e) { float v = row[lane + e * 64]; s = fmaf(v, v, s); }
    #pragma unroll
    for (int m = 32; m >= 1; m >>= 1) s += __shfl_xor(s, m, 64);
    if (lane == 0) cnorm[wid] = s;
}

/* ------ codebook prep: fp16 2-way split, tiled+swizzled for the GEMM ---- */
/* CbT layout: [q][term 2][mt 8][kt 8][8192], elem (m,kk) at short-off     */
/* (((m*128 + kk*2) ^ ((m&7)<<4)) >> 1); k = ci = kt*64+kk                 */
__global__ void cbprep_kernel(const float* __restrict__ cb, half_t* __restrict__ CbT) {
    int idx = blockIdx.x * 256 + threadIdx.x;     /* 8*8*8*8192 = 4194304 */
    int e  = idx & 8191;
    int kt = (idx >> 13) & 7;
    int mt = (idx >> 16) & 7;
    int q  = idx >> 19;
    int m = e >> 6, kk = e & 63;
    int ci = kt * 64 + kk;
    int code = mt * 128 + m;
    float v = cb[((size_t)(q * NV + code)) * NC + ci];
    half_t h1, h2;
    split64(v, h1, h2);
    int off = ((m * 128 + kk * 2) ^ ((m & 7) << 4)) >> 1;
    size_t base = ((((size_t)q * 2 + 0) * 8 + mt) * 8 + kt) * 8192 + off;
    CbT[base] = h1;
    CbT[base + (size_t)8 * 8 * 8192] = h2;        /* term stride within q */
}

/* ------------- window-mean downsample of (z - zhat) -> fp16 split ------ */
/* Coalesced tile-transpose version: block = (b, 64 channels).             */
/* Phase 1: float4-coalesced read of z/zhat -> LDS diff tile D[64][129].   */
/* Phase 2: per-(c,j) window sum over w from LDS, split, 128B-chunk write. */
__global__ __launch_bounds__(256) void downsample_split_kernel(
        const float* __restrict__ z, const float* __restrict__ zhat,
        half_t* __restrict__ Xd1, half_t* __restrict__ Xd2,
        int s, int log2s) {
    __shared__ float D[64 * 129];
    const int tid = threadIdx.x;
    const int b  = blockIdx.x;           /* 0..63  */
    const int c0 = blockIdx.y << 6;      /* 0..448 */
    const size_t gbase = ((size_t)(b * NC + c0)) * NT;   /* 8192 floats, 16B-aligned */
    #pragma unroll
    for (int i = 0; i < 8; ++i) {
        int idx4 = (i * 256 + tid) * 4;
        float4 zv = *(const float4*)(z    + gbase + idx4);
        float4 hv = *(const float4*)(zhat + gbase + idx4);
        int cc = idx4 >> 7, t = idx4 & 127;
        float* dp = D + cc * 129 + t;
        dp[0] = zv.x - hv.x; dp[1] = zv.y - hv.y; dp[2] = zv.z - hv.z; dp[3] = zv.w - hv.w;
    }
    __syncthreads();
    const int w = NT >> log2s;
    const float invw = 1.f / (float)w;
    for (int idx = tid; idx < (s << 6); idx += 256) {
        int cc = idx & 63;               /* lanes span channels -> conflict-free + coalesced */
        int j  = idx >> 6;
        const float* row = D + cc * 129 + j * w;
        float sum = 0.f;
        for (int i = 0; i < w; ++i) sum += row[i];
        float xd = sum * invw;
        half_t h1, h2;
        split1(xd, h1, h2);
        size_t o = ((size_t)(b * s + j)) * NC + c0 + cc;
        Xd1[o] = h1;
        Xd2[o] = h2;
    }
}

/* ---- quant: fp16x2 MFMA distance GEMM + fused per-block argmin --------- */
/* grid (R/64, 8mt), 256 thr. A = codebook tile (128 codes x 64k),         */
/* B = xd rows (64 x 64k). dist = cnorm - 2*(accM/64 + accm/4096)          */
__global__ __launch_bounds__(256, 2) void quant_mfma_kernel(
        const half_t* __restrict__ CbTq,
        const half_t* __restrict__ Xd1, const half_t* __restrict__ Xd2,
        const float* __restrict__ cnorm,
        float* __restrict__ pval, int* __restrict__ pidx) {
    __shared__ half_t As1[8192];
    __shared__ half_t As2[8192];
    __shared__ half_t Bs1[4096];
    __shared__ half_t Bs2[4096];
    __shared__ float redv[2][2][2][16];
    __shared__ int   redi[2][2][2][16];
    const int tid = threadIdx.x;
    const int w = tid >> 6, l = tid & 63;
    const int wm = w >> 1, wn = w & 1;
    const int lane16 = l & 15, lhi = l >> 4;
    const int nblk = blockIdx.x, mt = blockIdx.y;
    const int r0 = nblk * 64;
    f32x4 accM[4][2] = {}, accm[4][2] = {};
    const half_t* C1b = CbTq + ((size_t)(0 * 8 + mt)) * (8 * 8192);
    const half_t* C2b = CbTq + ((size_t)(1 * 8 + mt)) * (8 * 8192);
    for (int kt = 0; kt < 8; ++kt) {
        const int ci0 = kt << 6;
        __syncthreads();
        const char* c1src = (const char*)(C1b + (size_t)kt * 8192);
        const char* c2src = (const char*)(C2b + (size_t)kt * 8192);
        #pragma unroll
        for (int i = 0; i < 4; ++i) {
            GLD16(c1src + (i * 256 + tid) * 16, (char*)As1 + i * 4096 + w * 1024);
            GLD16(c2src + (i * 256 + tid) * 16, (char*)As2 + i * 4096 + w * 1024);
        }
        #pragma unroll
        for (int i = 0; i < 2; ++i) {
            int c = i * 256 + tid;
            int n = c >> 3, sub = c & 7;
            size_t soff = ((size_t)(r0 + n)) * NC + ci0 + ((sub ^ (n & 7)) << 3);
            GLD16(Xd1 + soff, (char*)Bs1 + i * 4096 + w * 1024);
            GLD16(Xd2 + soff, (char*)Bs2 + i * 4096 + w * 1024);
        }
        __syncthreads();
        #pragma unroll
        for (int kstep = 0; kstep < 2; ++kstep) {
            const int kb = (kstep * 32 + lhi * 8) * 2;
            f16x8 a1[4], a2[4], b1[2], b2[2];
            #pragma unroll
            for (int im = 0; im < 4; ++im) {
                int m = wm * 64 + im * 16 + lane16;
                int off = (m * 128 + kb) ^ ((m & 7) << 4);
                a1[im] = *(const f16x8*)((const char*)As1 + off);
                a2[im] = *(const f16x8*)((const char*)As2 + off);
            }
            #pragma unroll
            for (int in = 0; in < 2; ++in) {
                int n = wn * 32 + in * 16 + lane16;
                int off = (n * 128 + kb) ^ ((n & 7) << 4);
                b1[in] = *(const f16x8*)((const char*)Bs1 + off);
                b2[in] = *(const f16x8*)((const char*)Bs2 + off);
            }
            #pragma unroll
            for (int im = 0; im < 4; ++im)
                #pragma unroll
                for (int in = 0; in < 2; ++in) {
                    accM[im][in] = __builtin_amdgcn_mfma_f32_16x16x32_f16(a1[im], b1[in], accM[im][in], 0, 0, 0);
                    accm[im][in] = __builtin_amdgcn_mfma_f32_16x16x32_f16(a1[im], b2[in], accm[im][in], 0, 0, 0);
                    accm[im][in] = __builtin_amdgcn_mfma_f32_16x16x32_f16(a2[im], b1[in], accm[im][in], 0, 0, 0);
                }
        }
    }
    /* fused argmin: per-lane over 16 codes (ascending), xor-shuffle over lhi,
       cross-wave(wm) via LDS. first-min tie-break = lowest code index. */
    float bv[2] = {1e30f, 1e30f};
    int   bi[2] = {0, 0};
    #pragma unroll
    for (int im = 0; im < 4; ++im) {
        int mb = mt * 128 + wm * 64 + im * 16 + lhi * 4;
        float4 cn = *(const float4*)(cnorm + mb);
        const float* cnp = (const float*)&cn;
        #pragma unroll
        for (int in = 0; in < 2; ++in) {
            #pragma unroll
            for (int r = 0; r < 4; ++r) {
                float d = cnp[r] - 2.f * (accM[im][in][r] * SC_MAIN + accm[im][in][r] * SC_MID);
                int code = mb + r;
                if (d < bv[in]) { bv[in] = d; bi[in] = code; }
            }
        }
    }
    #pragma unroll
    for (int m = 16; m <= 32; m <<= 1) {
        #pragma unroll
        for (int in = 0; in < 2; ++in) {
            float ov = __shfl_xor(bv[in], m, 64);
            int   oi = __shfl_xor(bi[in], m, 64);
            if (ov < bv[in] || (ov == bv[in] && oi < bi[in])) { bv[in] = ov; bi[in] = oi; }
        }
    }
    if (lhi == 0) {
        #pragma unroll
        for (int in = 0; in < 2; ++in) { redv[wm][wn][in][lane16] = bv[in]; redi[wm][wn][in][lane16] = bi[in]; }
    }
    __syncthreads();
    if (wm == 0 && lhi == 0) {
        #pragma unroll
        for (int in = 0; in < 2; ++in) {
            float v0 = redv[0][wn][in][lane16]; int i0 = redi[0][wn][in][lane16];
            float v1 = redv[1][wn][in][lane16]; int i1 = redi[1][wn][in][lane16];
            if (v1 < v0 || (v1 == v0 && i1 < i0)) { v0 = v1; i0 = i1; }
            int r = r0 + wn * 32 + in * 16 + lane16;
            pval[(size_t)r * 8 + mt] = v0;
            pidx[(size_t)r * 8 + mt] = i0;
        }
    }
}

/* ------------------------------------- cross-block argmin + idx + counts */
__global__ void argmin_final_kernel(const float* __restrict__ pval, const int* __restrict__ pidx,
                                    int* __restrict__ idx_int, int* __restrict__ counts,
                                    float* __restrict__ out_idx, int R, int s, int log2s, int offq) {
    int r = blockIdx.x * 256 + threadIdx.x;
    if (r >= R) return;
    float bv = 1e30f; int bi = 0;
    #pragma unroll
    for (int k = 0; k < 8; ++k) {
        float v = pval[(size_t)r * 8 + k];
        int   i = pidx[(size_t)r * 8 + k];
        if (v < bv || (v == bv && i < bi)) { bv = v; bi = i; }
    }
    idx_int[r] = bi;
    atomicAdd(&counts[bi], 1);
    int b = r >> log2s, j = r & (s - 1);
    out_idx[(size_t)b * IDX_STRIDE + offq + j] = (float)bi;
}

/* ----------------- upsample + fp16 split, padded Xt layout -------------- */
/* X*[b][130][512]; rows 0,129 zero pads; row t+1 holds time t             */
__global__ void upsample_split_kernel(const float* __restrict__ cb, const int* __restrict__ idx_int,
                                      half_t* __restrict__ X1, half_t* __restrict__ X2, int s) {
    int b = blockIdx.x, tp = blockIdx.y, c = threadIdx.x;
    size_t off = ((size_t)b * 130 + tp) * NC + c;
    if (tp == 0 || tp == 129) { X1[off] = (half_t)0.f; X2[off] = (half_t)0.f; return; }
    int t = tp - 1;
    float in = (t + 0.5f) * ((float)s * (1.f / 128.f)) - 0.5f;
    float jf = floorf(in);
    float f = in - jf;
    int j0 = (int)jf;
    int i0 = min(max(j0, 0), s - 1);
    int i1 = min(max(j0 + 1, 0), s - 1);
    const int* ib = idx_int + b * s;
    float v0 = cb[(size_t)ib[i0] * NC + c];
    float v1 = cb[(size_t)ib[i1] * NC + c];
    float v = (1.f - f) * v0 + f * v1;
    half_t h1, h2;
    split1(v, h1, h2);
    X1[off] = h1; X2[off] = h2;
}

/* ----- weight prep: fp16 2-way split, tile+swizzle for the conv GEMM ---- */
/* Wt per conv: [term 2][mt 4][kt 24][8192]; k = ks*512 + ci               */
__global__ void wprep_kernel(const float* __restrict__ W /* [2][512][512][3] */,
                             half_t* __restrict__ Wt) {
    int d = blockIdx.y;
    const float* Wd = W + (size_t)d * NC * NC * 3;
    half_t* Wtd = Wt + (size_t)d * (2 * 4 * 24 * 8192);
    int idx = blockIdx.x * 256 + threadIdx.x;      /* 786432 = 4*24*8192 */
    int e  = idx & 8191;
    int rest = idx >> 13;
    int kt = rest % 24;
    int mtl = rest / 24;
    int m = e >> 6, kk = e & 63;
    int k = kt * 64 + kk;
    int ks = k >> 9, ci = k & 511;
    int co = mtl * 128 + m;
    float v = Wd[((size_t)co * NC + ci) * 3 + ks];
    half_t h1, h2;
    split64(v, h1, h2);
    int off = ((m * 128 + kk * 2) ^ ((m & 7) << 4)) >> 1;
    size_t base = ((size_t)mtl * 24 + kt) * 8192 + off;
    Wtd[base] = h1;
    Wtd[base + (size_t)4 * 24 * 8192] = h2;
}

/* -------- conv1d as fp16x2 MFMA GEMM, kt-major dual-term staging -------- */
/* MODE 0: y=relu(...); split -> Y1/Y2 (padded layout)                      */
/* MODE 1: y=relu(...); zhat+=y; fused loss partial sum -> lpart[block]     */
template<int MODE>
__global__ __launch_bounds__(256, 2) void conv_mfma_kernel(
        const half_t* __restrict__ Wt,
        const half_t* __restrict__ X1, const half_t* __restrict__ X2,
        const float* __restrict__ bias,
        half_t* __restrict__ Y1, half_t* __restrict__ Y2,
        float* __restrict__ zhat, const float* __restrict__ z,
        float* __restrict__ lpart) {
    __shared__ half_t As1[8192];
    __shared__ half_t As2[8192];
    __shared__ half_t Bs1[4096];
    __shared__ half_t Bs2[4096];
    const int tid = threadIdx.x;
    const int w = tid >> 6, l = tid & 63;
    const int wm = w >> 1, wn = w & 1;
    const int lane16 = l & 15, lhi = l >> 4;
    const int nblk = blockIdx.x, mt = blockIdx.y;
    const int b = nblk >> 1, t0 = (nblk & 1) << 6;
    f32x4 accM[4][2] = {}, accm[4][2] = {};
    const half_t* W1b = Wt + ((size_t)(0 * 4 + mt)) * (24 * 8192);
    const half_t* W2b = Wt + ((size_t)(1 * 4 + mt)) * (24 * 8192);
    for (int kt = 0; kt < 24; ++kt) {
        const int ks  = kt >> 3;
        const int ci0 = (kt & 7) << 6;
        const int rowb = b * 130 + t0 + ks;
        __syncthreads();
        const char* w1src = (const char*)(W1b + (size_t)kt * 8192);
        const char* w2src = (const char*)(W2b + (size_t)kt * 8192);
        #pragma unroll
        for (int i = 0; i < 4; ++i) {
            GLD16(w1src + (i * 256 + tid) * 16, (char*)As1 + i * 4096 + w * 1024);
            GLD16(w2src + (i * 256 + tid) * 16, (char*)As2 + i * 4096 + w * 1024);
        }
        #pragma unroll
        for (int i = 0; i < 2; ++i) {
            int c = i * 256 + tid;
            int n = c >> 3, sub = c & 7;
            size_t soff = ((size_t)(rowb + n)) * NC + ci0 + ((sub ^ (n & 7)) << 3);
            GLD16(X1 + soff, (char*)Bs1 + i * 4096 + w * 1024);
            GLD16(X2 + soff, (char*)Bs2 + i * 4096 + w * 1024);
        }
        __syncthreads();
        #pragma unroll
        for (int kstep = 0; kstep < 2; ++kstep) {
            const int kb = (kstep * 32 + lhi * 8) * 2;
            f16x8 a1[4], a2[4], b1[2], b2[2];
            #pragma unroll
            for (int im = 0; im < 4; ++im) {
                int m = wm * 64 + im * 16 + lane16;
                int off = (m * 128 + kb) ^ ((m & 7) << 4);
                a1[im] = *(const f16x8*)((const char*)As1 + off);
                a2[im] = *(const f16x8*)((const char*)As2 + off);
            }
            #pragma unroll
            for (int in = 0; in < 2; ++in) {
                int n = wn * 32 + in * 16 + lane16;
                int off = (n * 128 + kb) ^ ((n & 7) << 4);
                b1[in] = *(const f16x8*)((const char*)Bs1 + off);
                b2[in] = *(const f16x8*)((const char*)Bs2 + off);
            }
            #pragma unroll
            for (int im = 0; im < 4; ++im)
                #pragma unroll
                for (int in = 0; in < 2; ++in) {
                    accM[im][in] = __builtin_amdgcn_mfma_f32_16x16x32_f16(a1[im], b1[in], accM[im][in], 0, 0, 0);
                    accm[im][in] = __builtin_amdgcn_mfma_f32_16x16x32_f16(a1[im], b2[in], accm[im][in], 0, 0, 0);
                    accm[im][in] = __builtin_amdgcn_mfma_f32_16x16x32_f16(a2[im], b1[in], accm[im][in], 0, 0, 0);
                }
        }
    }
    /* epilogue: C/D layout col=lane&15 (n), row=lhi*4+reg (m) */
    float lsum = 0.f;
    #pragma unroll
    for (int im = 0; im < 4; ++im) {
        int mb = mt * 128 + wm * 64 + im * 16 + lhi * 4;
        float bs[4];
        #pragma unroll
        for (int r = 0; r < 4; ++r) bs[r] = bias[mb + r];
        #pragma unroll
        for (int in = 0; in < 2; ++in) {
            int t = t0 + wn * 32 + in * 16 + lane16;
            if (MODE == 0) {
                half_t h1v[4], h2v[4];
                #pragma unroll
                for (int r = 0; r < 4; ++r) {
                    float y = accM[im][in][r] * SC_MAIN + accm[im][in][r] * SC_MID + bs[r];
                    y = y > 0.f ? y : 0.f;
                    split1(y, h1v[r], h2v[r]);
                }
                size_t rowoff = ((size_t)(b * 130 + 1 + t)) * NC + mb;
                *(ushort4*)(Y1 + rowoff) = *(const ushort4*)h1v;
                *(ushort4*)(Y2 + rowoff) = *(const ushort4*)h2v;
            } else {
                size_t base = ((size_t)b * NC + mb) * NT + t;
                #pragma unroll
                for (int r = 0; r < 4; ++r) {
                    float y = accM[im][in][r] * SC_MAIN + accm[im][in][r] * SC_MID + bs[r];
                    y = y > 0.f ? y : 0.f;
                    size_t oi = base + (size_t)r * NT;
                    float zn = zhat[oi] + y;
                    zhat[oi] = zn;
                    float d = zn - z[oi];
                    lsum = fmaf(d, d, lsum);
                }
            }
        }
    }
    if (MODE == 1) {
        __syncthreads();
        float* red = (float*)As1;
        red[tid] = lsum;
        __syncthreads();
        for (int st = 128; st >= 1; st >>= 1) {
            if (tid < st) red[tid] += red[tid + st];
            __syncthreads();
        }
        if (tid == 0) lpart[blockIdx.y * 128 + blockIdx.x] = red[0];
    }
}

/* --------------------- per-scale: finalize loss + usage + perplexity --- */
__global__ void scale_final_kernel(const float* __restrict__ lpart, const int* __restrict__ counts,
                                   float* __restrict__ accums, float invBS) {
    __shared__ float sm[256];
    __shared__ float se[256];
    __shared__ int   su[256];
    int tid = threadIdx.x;
    float ls = lpart[tid] + lpart[tid + 256];
    int used = 0; float ent = 0.f;
    #pragma unroll
    for (int k = 0; k < 4; ++k) {
        int cv = counts[tid + k * 256];
        if (cv > 0) used++;
        float p = (float)cv * invBS;
        ent = fmaf(p, logf(p + 1e-10f), ent);
    }
    sm[tid] = ls; se[tid] = ent; su[tid] = used;
    __syncthreads();
    for (int st = 128; st >= 1; st >>= 1) {
        if (tid < st) { sm[tid] += sm[tid + st]; se[tid] += se[tid + st]; su[tid] += su[tid + st]; }
        __syncthreads();
    }
    if (tid == 0) {
        float m = sm[0] * (1.f / (float)NBIG);
        accums[1] += 0.25f * m + m;                        /* (beta+1)*mse  */
        accums[0] += ((float)su[0] * (1.f / 1024.f)) * 100.f;
        accums[2] += expf(-se[0]);
    }
}

__global__ void final_write_kernel(const float* __restrict__ accums, float* __restrict__ outscal) {
    int t = threadIdx.x;
    if (t < 3) outscal[t] = accums[t] * 0.125f;            /* /= nQ */
}

/* ====================================================================== */
extern "C" void kernel_launch(void* const* d_in, const int* in_sizes, int n_in,
                              void* d_out, int out_size, void* d_ws, size_t ws_size,
                              hipStream_t stream) {
    const float* z  = (const float*)d_in[0];
    const float* cb = (const float*)d_in[1];
    const float* pw = (const float*)d_in[2];
    const float* pb = (const float*)d_in[3];

    float* zhat     = (float*)d_out;
    float* out_scal = zhat + NBIG;
    float* out_idx  = zhat + NBIG + 3;

    char* w = (char*)d_ws;
    half_t* Xd1 = (half_t*)w;  w += (size_t)8192 * NC * 2;
    half_t* Xd2 = (half_t*)w;  w += (size_t)8192 * NC * 2;
    half_t* Xa1 = (half_t*)w;  w += (size_t)NB * 130 * NC * 2;
    half_t* Xa2 = (half_t*)w;  w += (size_t)NB * 130 * NC * 2;
    half_t* Xb1 = (half_t*)w;  w += (size_t)NB * 130 * NC * 2;
    half_t* Xb2 = (half_t*)w;  w += (size_t)NB * 130 * NC * 2;
    half_t* Wt  = (half_t*)w;  w += (size_t)2 * 2 * 4 * 24 * 8192 * 2;   /* 2 convs */
    half_t* CbT = (half_t*)w;  w += (size_t)NQ * 2 * 8 * 8 * 8192 * 2;
    float* pval  = (float*)w;  w += (size_t)8192 * 8 * 4;
    int*   pidx  = (int*)w;    w += (size_t)8192 * 8 * 4;
    int*   idx_i = (int*)w;    w += (size_t)16384 * 4;
    int*   counts= (int*)w;    w += (size_t)NQ * NV * 4;
    float* cnorm = (float*)w;  w += (size_t)NQ * NV * 4;
    float* lpart = (float*)w;  w += (size_t)512 * 4;
    float* accums= (float*)w;  w += 256;

    init_kernel<<<2048, 256, 0, stream>>>(zhat, counts, accums);
    padzero_kernel<<<dim3(64, 2), 512, 0, stream>>>(Xb1, Xb2);
    cnorm_kernel<<<(NQ * NV) / 4, 256, 0, stream>>>(cb, cnorm);
    cbprep_kernel<<<16384, 256, 0, stream>>>(cb, CbT);

    const size_t WT_CONV = (size_t)2 * 4 * 24 * 8192;   /* halves per conv */
    int offq = 0;
    for (int q = 0; q < NQ; ++q) {
        int s = 1 << q;
        int R = NB * s;
        const float* cbq = cb + (size_t)q * NV * NC;
        const float* wq  = pw + (size_t)q * 2 * NC * NC * 3;
        const float* bq0 = pb + (size_t)q * 2 * NC;
        const float* bq1 = bq0 + NC;

        downsample_split_kernel<<<dim3(64, 8), 256, 0, stream>>>(z, zhat, Xd1, Xd2, s, q);
        quant_mfma_kernel<<<dim3(R / 64, 8), 256, 0, stream>>>(
            CbT + (size_t)q * 2 * 8 * 8 * 8192, Xd1, Xd2, cnorm + q * NV, pval, pidx);
        argmin_final_kernel<<<(R + 255) / 256, 256, 0, stream>>>(pval, pidx, idx_i,
                                                                 counts + q * NV, out_idx, R, s, q, offq);
        upsample_split_kernel<<<dim3(64, 130), 512, 0, stream>>>(cbq, idx_i, Xa1, Xa2, s);
        wprep_kernel<<<dim3(3072, 2), 256, 0, stream>>>(wq, Wt);
        conv_mfma_kernel<0><<<dim3(128, 4), 256, 0, stream>>>(
            Wt, Xa1, Xa2, bq0, Xb1, Xb2, nullptr, nullptr, nullptr);
        conv_mfma_kernel<1><<<dim3(128, 4), 256, 0, stream>>>(
            Wt + WT_CONV, Xb1, Xb2, bq1, nullptr, nullptr, zhat, z, lpart);
        scale_final_kernel<<<1, 256, 0, stream>>>(lpart, counts + q * NV, accums, 1.f / (float)(NB * s));
        offq += s;
    }
    final_write_kernel<<<1, 64, 0, stream>>>(accums, out_scal);
}

// Round 5
// 1022.213 us; speedup vs baseline: 3.7439x; 1.0271x over previous
//
#include <hip/hip_runtime.h>
#include <math.h>

#define NB 64
#define NC 512
#define NT 128
#define NQ 8
#define NV 1024
#define NBIG 4194304      /* NB*NC*NT */
#define IDX_STRIDE 255

typedef _Float16 half_t;
typedef half_t f16x8 __attribute__((ext_vector_type(8)));
typedef float  f32x4 __attribute__((ext_vector_type(4)));

#define SC_MAIN 0.015625f           /* 2^-6  */
#define SC_MID  2.44140625e-4f      /* 2^-12 */

#define GLD16(g, l) __builtin_amdgcn_global_load_lds( \
    (const __attribute__((address_space(1))) unsigned int*)(g), \
    (__attribute__((address_space(3))) unsigned int*)(l), 16, 0, 0)

/* A-side split: W1 = fp16(64v), W2 = fp16((64v - W1)*64)  -> v = W1/64 + W2/4096 + O(2^-24 v) */
__device__ inline void split64(float v, half_t& h1, half_t& h2) {
    half_t a = (half_t)(v * 64.f);
    float r = v * 64.f - (float)a;
    h1 = a;
    h2 = (half_t)(r * 64.f);
}
/* X-side split: X1 = fp16(v), X2 = fp16((v - X1)*64)      -> v = X1 + X2/64 + O(2^-24 v) */
__device__ inline void split1(float v, half_t& h1, half_t& h2) {
    half_t a = (half_t)v;
    float r = v - (float)a;
    h1 = a;
    h2 = (half_t)(r * 64.f);
}

/* ------------------------------------------------------------------ init */
__global__ void init_kernel(float* __restrict__ zhat, int* __restrict__ counts,
                            float* __restrict__ accums) {
    int i = blockIdx.x * 256 + threadIdx.x;
    const int stride = 2048 * 256;
    for (; i < NBIG; i += stride) {
        zhat[i] = 0.f;
        if (i < NQ * NV) counts[i] = 0;
        if (i < 16)      accums[i] = 0.f;
    }
}

/* zero pad rows (t=-1 and t=128) of the Xb (hidden) buffers, once per call */
__global__ void padzero_kernel(half_t* __restrict__ X1, half_t* __restrict__ X2) {
    int b = blockIdx.x;
    int row = blockIdx.y ? 129 : 0;
    int c = threadIdx.x;
    size_t off = ((size_t)b * 130 + row) * NC + c;
    X1[off] = (half_t)0.f; X2[off] = (half_t)0.f;
}

/* --------------------------------------------------- codebook |c|^2 rows */
__global__ void cnorm_kernel(const float* __restrict__ cb, float* __restrict__ cnorm) {
    int wid  = (blockIdx.x * 256 + threadIdx.x) >> 6;
    int lane = threadIdx.x & 63;
    if (wid >= NQ * NV) return;
    const float* row = cb + (size_t)wid * NC;
    float s = 0.f;
    #pragma unroll
    for (int e = 0; e < NC / 64; ++e) { float v = row[lane + e * 64]; s = fmaf(v, v, s); }
    #pragma unroll
    for (int m = 32; m >= 1; m >>= 1) s += __shfl_xor(s, m, 64);
    if (lane == 0) cnorm[wid] = s;
}

/* ------ codebook prep: fp16 2-way split, tiled+swizzled for the GEMM ---- */
/* CbT layout: [q][term 2][mt 8][kt 8][8192], elem (m,kk) at short-off     */
/* (((m*128 + kk*2) ^ ((m&7)<<4)) >> 1); k = ci = kt*64+kk                 */
__global__ void cbprep_kernel(const float* __restrict__ cb, half_t* __restrict__ CbT) {
    int idx = blockIdx.x * 256 + threadIdx.x;     /* 8*8*8*8192 = 4194304 */
    int e  = idx & 8191;
    int kt = (idx >> 13) & 7;
    int mt = (idx >> 16) & 7;
    int q  = idx >> 19;
    int m = e >> 6, kk = e & 63;
    int ci = kt * 64 + kk;
    int code = mt * 128 + m;
    float v = cb[((size_t)(q * NV + code)) * NC + ci];
    half_t h1, h2;
    split64(v, h1, h2);
    int off = ((m * 128 + kk * 2) ^ ((m & 7) << 4)) >> 1;
    size_t base = ((((size_t)q * 2 + 0) * 8 + mt) * 8 + kt) * 8192 + off;
    CbT[base] = h1;
    CbT[base + (size_t)8 * 8 * 8192] = h2;        /* term stride within q */
}

/* ------------- window-mean downsample of (z - zhat) -> fp16 split ------ */
/* Coalesced tile-transpose version: block = (b, 64 channels).             */
__global__ __launch_bounds__(256) void downsample_split_kernel(
        const float* __restrict__ z, const float* __restrict__ zhat,
        half_t* __restrict__ Xd1, half_t* __restrict__ Xd2,
        int s, int log2s) {
    __shared__ float D[64 * 129];
    const int tid = threadIdx.x;
    const int b  = blockIdx.x;           /* 0..63  */
    const int c0 = blockIdx.y << 6;      /* 0..448 */
    const size_t gbase = ((size_t)(b * NC + c0)) * NT;   /* 8192 floats */
    #pragma unroll
    for (int i = 0; i < 8; ++i) {
        int idx4 = (i * 256 + tid) * 4;
        float4 zv = *(const float4*)(z    + gbase + idx4);
        float4 hv = *(const float4*)(zhat + gbase + idx4);
        int cc = idx4 >> 7, t = idx4 & 127;
        float* dp = D + cc * 129 + t;
        dp[0] = zv.x - hv.x; dp[1] = zv.y - hv.y; dp[2] = zv.z - hv.z; dp[3] = zv.w - hv.w;
    }
    __syncthreads();
    const int w = NT >> log2s;
    const float invw = 1.f / (float)w;
    for (int idx = tid; idx < (s << 6); idx += 256) {
        int cc = idx & 63;
        int j  = idx >> 6;
        const float* row = D + cc * 129 + j * w;
        float sum = 0.f;
        for (int i = 0; i < w; ++i) sum += row[i];
        float xd = sum * invw;
        half_t h1, h2;
        split1(xd, h1, h2);
        size_t o = ((size_t)(b * s + j)) * NC + c0 + cc;
        Xd1[o] = h1;
        Xd2[o] = h2;
    }
}

/* ---- quant: fp16x2 MFMA distance GEMM + fused per-block argmin --------- */
__global__ __launch_bounds__(256, 2) void quant_mfma_kernel(
        const half_t* __restrict__ CbTq,
        const half_t* __restrict__ Xd1, const half_t* __restrict__ Xd2,
        const float* __restrict__ cnorm,
        float* __restrict__ pval, int* __restrict__ pidx) {
    __shared__ half_t As1[8192];
    __shared__ half_t As2[8192];
    __shared__ half_t Bs1[4096];
    __shared__ half_t Bs2[4096];
    __shared__ float redv[2][2][2][16];
    __shared__ int   redi[2][2][2][16];
    const int tid = threadIdx.x;
    const int w = tid >> 6, l = tid & 63;
    const int wm = w >> 1, wn = w & 1;
    const int lane16 = l & 15, lhi = l >> 4;
    const int nblk = blockIdx.x, mt = blockIdx.y;
    const int r0 = nblk * 64;
    f32x4 accM[4][2] = {}, accm[4][2] = {};
    const half_t* C1b = CbTq + ((size_t)(0 * 8 + mt)) * (8 * 8192);
    const half_t* C2b = CbTq + ((size_t)(1 * 8 + mt)) * (8 * 8192);
    for (int kt = 0; kt < 8; ++kt) {
        const int ci0 = kt << 6;
        __syncthreads();
        const char* c1src = (const char*)(C1b + (size_t)kt * 8192);
        const char* c2src = (const char*)(C2b + (size_t)kt * 8192);
        #pragma unroll
        for (int i = 0; i < 4; ++i) {
            GLD16(c1src + (i * 256 + tid) * 16, (char*)As1 + i * 4096 + w * 1024);
            GLD16(c2src + (i * 256 + tid) * 16, (char*)As2 + i * 4096 + w * 1024);
        }
        #pragma unroll
        for (int i = 0; i < 2; ++i) {
            int c = i * 256 + tid;
            int n = c >> 3, sub = c & 7;
            size_t soff = ((size_t)(r0 + n)) * NC + ci0 + ((sub ^ (n & 7)) << 3);
            GLD16(Xd1 + soff, (char*)Bs1 + i * 4096 + w * 1024);
            GLD16(Xd2 + soff, (char*)Bs2 + i * 4096 + w * 1024);
        }
        __syncthreads();
        #pragma unroll
        for (int kstep = 0; kstep < 2; ++kstep) {
            const int kb = (kstep * 32 + lhi * 8) * 2;
            f16x8 a1[4], a2[4], b1[2], b2[2];
            #pragma unroll
            for (int im = 0; im < 4; ++im) {
                int m = wm * 64 + im * 16 + lane16;
                int off = (m * 128 + kb) ^ ((m & 7) << 4);
                a1[im] = *(const f16x8*)((const char*)As1 + off);
                a2[im] = *(const f16x8*)((const char*)As2 + off);
            }
            #pragma unroll
            for (int in = 0; in < 2; ++in) {
                int n = wn * 32 + in * 16 + lane16;
                int off = (n * 128 + kb) ^ ((n & 7) << 4);
                b1[in] = *(const f16x8*)((const char*)Bs1 + off);
                b2[in] = *(const f16x8*)((const char*)Bs2 + off);
            }
            #pragma unroll
            for (int im = 0; im < 4; ++im)
                #pragma unroll
                for (int in = 0; in < 2; ++in) {
                    accM[im][in] = __builtin_amdgcn_mfma_f32_16x16x32_f16(a1[im], b1[in], accM[im][in], 0, 0, 0);
                    accm[im][in] = __builtin_amdgcn_mfma_f32_16x16x32_f16(a1[im], b2[in], accm[im][in], 0, 0, 0);
                    accm[im][in] = __builtin_amdgcn_mfma_f32_16x16x32_f16(a2[im], b1[in], accm[im][in], 0, 0, 0);
                }
        }
    }
    float bv[2] = {1e30f, 1e30f};
    int   bi[2] = {0, 0};
    #pragma unroll
    for (int im = 0; im < 4; ++im) {
        int mb = mt * 128 + wm * 64 + im * 16 + lhi * 4;
        float4 cn = *(const float4*)(cnorm + mb);
        const float* cnp = (const float*)&cn;
        #pragma unroll
        for (int in = 0; in < 2; ++in) {
            #pragma unroll
            for (int r = 0; r < 4; ++r) {
                float d = cnp[r] - 2.f * (accM[im][in][r] * SC_MAIN + accm[im][in][r] * SC_MID);
                int code = mb + r;
                if (d < bv[in]) { bv[in] = d; bi[in] = code; }
            }
        }
    }
    #pragma unroll
    for (int m = 16; m <= 32; m <<= 1) {
        #pragma unroll
        for (int in = 0; in < 2; ++in) {
            float ov = __shfl_xor(bv[in], m, 64);
            int   oi = __shfl_xor(bi[in], m, 64);
            if (ov < bv[in] || (ov == bv[in] && oi < bi[in])) { bv[in] = ov; bi[in] = oi; }
        }
    }
    if (lhi == 0) {
        #pragma unroll
        for (int in = 0; in < 2; ++in) { redv[wm][wn][in][lane16] = bv[in]; redi[wm][wn][in][lane16] = bi[in]; }
    }
    __syncthreads();
    if (wm == 0 && lhi == 0) {
        #pragma unroll
        for (int in = 0; in < 2; ++in) {
            float v0 = redv[0][wn][in][lane16]; int i0 = redi[0][wn][in][lane16];
            float v1 = redv[1][wn][in][lane16]; int i1 = redi[1][wn][in][lane16];
            if (v1 < v0 || (v1 == v0 && i1 < i0)) { v0 = v1; i0 = i1; }
            int r = r0 + wn * 32 + in * 16 + lane16;
            pval[(size_t)r * 8 + mt] = v0;
            pidx[(size_t)r * 8 + mt] = i0;
        }
    }
}

/* ------------------------------------- cross-block argmin + idx + counts */
__global__ void argmin_final_kernel(const float* __restrict__ pval, const int* __restrict__ pidx,
                                    int* __restrict__ idx_int, int* __restrict__ counts,
                                    float* __restrict__ out_idx, int R, int s, int log2s, int offq) {
    int r = blockIdx.x * 256 + threadIdx.x;
    if (r >= R) return;
    float bv = 1e30f; int bi = 0;
    #pragma unroll
    for (int k = 0; k < 8; ++k) {
        float v = pval[(size_t)r * 8 + k];
        int   i = pidx[(size_t)r * 8 + k];
        if (v < bv || (v == bv && i < bi)) { bv = v; bi = i; }
    }
    idx_int[r] = bi;
    atomicAdd(&counts[bi], 1);
    int b = r >> log2s, j = r & (s - 1);
    out_idx[(size_t)b * IDX_STRIDE + offq + j] = (float)bi;
}

/* ----------------- upsample + fp16 split, padded Xt layout -------------- */
__global__ void upsample_split_kernel(const float* __restrict__ cb, const int* __restrict__ idx_int,
                                      half_t* __restrict__ X1, half_t* __restrict__ X2, int s) {
    int b = blockIdx.x, tp = blockIdx.y, c = threadIdx.x;
    size_t off = ((size_t)b * 130 + tp) * NC + c;
    if (tp == 0 || tp == 129) { X1[off] = (half_t)0.f; X2[off] = (half_t)0.f; return; }
    int t = tp - 1;
    float in = (t + 0.5f) * ((float)s * (1.f / 128.f)) - 0.5f;
    float jf = floorf(in);
    float f = in - jf;
    int j0 = (int)jf;
    int i0 = min(max(j0, 0), s - 1);
    int i1 = min(max(j0 + 1, 0), s - 1);
    const int* ib = idx_int + b * s;
    float v0 = cb[(size_t)ib[i0] * NC + c];
    float v1 = cb[(size_t)ib[i1] * NC + c];
    float v = (1.f - f) * v0 + f * v1;
    half_t h1, h2;
    split1(v, h1, h2);
    X1[off] = h1; X2[off] = h2;
}

/* ----- weight prep: fp16 2-way split, tile+swizzle for the conv GEMM ---- */
/* Wt per conv: [term 2][mt 4][kt 24][8192]; k = ks*512 + ci               */
__global__ void wprep_kernel(const float* __restrict__ W /* [2][512][512][3] */,
                             half_t* __restrict__ Wt) {
    int d = blockIdx.y;
    const float* Wd = W + (size_t)d * NC * NC * 3;
    half_t* Wtd = Wt + (size_t)d * (2 * 4 * 24 * 8192);
    int idx = blockIdx.x * 256 + threadIdx.x;      /* 786432 = 4*24*8192 */
    int e  = idx & 8191;
    int rest = idx >> 13;
    int kt = rest % 24;
    int mtl = rest / 24;
    int m = e >> 6, kk = e & 63;
    int k = kt * 64 + kk;
    int ks = k >> 9, ci = k & 511;
    int co = mtl * 128 + m;
    float v = Wd[((size_t)co * NC + ci) * 3 + ks];
    half_t h1, h2;
    split64(v, h1, h2);
    int off = ((m * 128 + kk * 2) ^ ((m & 7) << 4)) >> 1;
    size_t base = ((size_t)mtl * 24 + kt) * 8192 + off;
    Wtd[base] = h1;
    Wtd[base + (size_t)4 * 24 * 8192] = h2;
}

/* ----- conv1d as fp16x2 MFMA GEMM, 2-phase double-buffered prefetch ----- */
/* 512 thr, tile 128m x 128n (one batch per block), grid (64 b, 4 mt).     */
/* MODE 0: y=relu(...); split -> Y1/Y2 (padded layout)                      */
/* MODE 1: y=relu(...); zhat+=y; fused loss partial -> lpart[mt*64+b]       */
template<int MODE>
__global__ __launch_bounds__(512, 2) void conv_mfma_kernel(
        const half_t* __restrict__ Wt,
        const half_t* __restrict__ X1, const half_t* __restrict__ X2,
        const float* __restrict__ bias,
        half_t* __restrict__ Y1, half_t* __restrict__ Y2,
        float* __restrict__ zhat, const float* __restrict__ z,
        float* __restrict__ lpart) {
    /* two distinct static buffer sets -> compile-time disambiguation */
    __shared__ half_t A1a[8192], A2a[8192], B1a[8192], B2a[8192];
    __shared__ half_t A1b[8192], A2b[8192], B1b[8192], B2b[8192];
    const int tid = threadIdx.x;
    const int w = tid >> 6;
    const int wm = w >> 2, wn = w & 3;            /* 2m x 4n waves, 64x32 each */
    const int l = tid & 63, lane16 = l & 15, lhi = l >> 4;
    const int b = blockIdx.x, mt = blockIdx.y;
    f32x4 accM[4][2] = {}, accm[4][2] = {};
    const half_t* W1b = Wt + ((size_t)(0 * 4 + mt)) * (24 * 8192);
    const half_t* W2b = Wt + ((size_t)(1 * 4 + mt)) * (24 * 8192);

    auto stage = [&](half_t* dA1, half_t* dA2, half_t* dB1, half_t* dB2, int kt) {
        const int ks = kt >> 3, ci0 = (kt & 7) << 6;
        const char* s1 = (const char*)(W1b + (size_t)kt * 8192);
        const char* s2 = (const char*)(W2b + (size_t)kt * 8192);
        const int rowb0 = b * 130 + ks;
        #pragma unroll
        for (int i = 0; i < 2; ++i) {
            int doff = i * 8192 + w * 1024;
            GLD16(s1 + (i * 512 + tid) * 16, (char*)dA1 + doff);
            GLD16(s2 + (i * 512 + tid) * 16, (char*)dA2 + doff);
            int c = i * 512 + tid, n = c >> 3, sub = c & 7;
            size_t soff = (size_t)(rowb0 + n) * NC + ci0 + ((sub ^ (n & 7)) << 3);
            GLD16(X1 + soff, (char*)dB1 + doff);
            GLD16(X2 + soff, (char*)dB2 + doff);
        }
    };
    auto compute = [&](const half_t* A1, const half_t* A2, const half_t* B1, const half_t* B2) {
        #pragma unroll
        for (int kstep = 0; kstep < 2; ++kstep) {
            const int kb = kstep * 64 + lhi * 16;
            f16x8 a1[4], a2[4], b1[2], b2[2];
            #pragma unroll
            for (int im = 0; im < 4; ++im) {
                int m = wm * 64 + im * 16 + lane16;
                int off = (m * 128 + kb) ^ ((m & 7) << 4);
                a1[im] = *(const f16x8*)((const char*)A1 + off);
                a2[im] = *(const f16x8*)((const char*)A2 + off);
            }
            #pragma unroll
            for (int in = 0; in < 2; ++in) {
                int n = wn * 32 + in * 16 + lane16;
                int off = (n * 128 + kb) ^ ((n & 7) << 4);
                b1[in] = *(const f16x8*)((const char*)B1 + off);
                b2[in] = *(const f16x8*)((const char*)B2 + off);
            }
            #pragma unroll
            for (int im = 0; im < 4; ++im)
                #pragma unroll
                for (int in = 0; in < 2; ++in) {
                    accM[im][in] = __builtin_amdgcn_mfma_f32_16x16x32_f16(a1[im], b1[in], accM[im][in], 0, 0, 0);
                    accm[im][in] = __builtin_amdgcn_mfma_f32_16x16x32_f16(a1[im], b2[in], accm[im][in], 0, 0, 0);
                    accm[im][in] = __builtin_amdgcn_mfma_f32_16x16x32_f16(a2[im], b1[in], accm[im][in], 0, 0, 0);
                }
        }
    };

    stage(A1a, A2a, B1a, B2a, 0);
    __syncthreads();
    #pragma unroll 1
    for (int k2 = 0; k2 < 12; ++k2) {
        stage(A1b, A2b, B1b, B2b, 2 * k2 + 1);
        compute(A1a, A2a, B1a, B2a);
        __syncthreads();
        if (k2 < 11) stage(A1a, A2a, B1a, B2a, 2 * k2 + 2);
        compute(A1b, A2b, B1b, B2b);
        __syncthreads();
    }

    /* epilogue: C/D layout col=lane&15 (n), row=lhi*4+reg (m) */
    float lsum = 0.f;
    #pragma unroll
    for (int im = 0; im < 4; ++im) {
        int mb = mt * 128 + wm * 64 + im * 16 + lhi * 4;
        float bs[4];
        #pragma unroll
        for (int r = 0; r < 4; ++r) bs[r] = bias[mb + r];
        #pragma unroll
        for (int in = 0; in < 2; ++in) {
            int t = wn * 32 + in * 16 + lane16;
            if (MODE == 0) {
                half_t h1v[4], h2v[4];
                #pragma unroll
                for (int r = 0; r < 4; ++r) {
                    float y = accM[im][in][r] * SC_MAIN + accm[im][in][r] * SC_MID + bs[r];
                    y = y > 0.f ? y : 0.f;
                    split1(y, h1v[r], h2v[r]);
                }
                size_t rowoff = ((size_t)(b * 130 + 1 + t)) * NC + mb;
                *(ushort4*)(Y1 + rowoff) = *(const ushort4*)h1v;
                *(ushort4*)(Y2 + rowoff) = *(const ushort4*)h2v;
            } else {
                size_t base = ((size_t)b * NC + mb) * NT + t;
                #pragma unroll
                for (int r = 0; r < 4; ++r) {
                    float y = accM[im][in][r] * SC_MAIN + accm[im][in][r] * SC_MID + bs[r];
                    y = y > 0.f ? y : 0.f;
                    size_t oi = base + (size_t)r * NT;
                    float zn = zhat[oi] + y;
                    zhat[oi] = zn;
                    float d = zn - z[oi];
                    lsum = fmaf(d, d, lsum);
                }
            }
        }
    }
    if (MODE == 1) {
        __syncthreads();
        float* red = (float*)A1a;
        red[tid] = lsum;
        __syncthreads();
        for (int st = 256; st >= 1; st >>= 1) {
            if (tid < st) red[tid] += red[tid + st];
            __syncthreads();
        }
        if (tid == 0) lpart[blockIdx.y * 64 + blockIdx.x] = red[0];
    }
}

/* --------------------- per-scale: finalize loss + usage + perplexity --- */
__global__ void scale_final_kernel(const float* __restrict__ lpart, const int* __restrict__ counts,
                                   float* __restrict__ accums, float invBS) {
    __shared__ float sm[256];
    __shared__ float se[256];
    __shared__ int   su[256];
    int tid = threadIdx.x;
    float ls = lpart[tid];
    int used = 0; float ent = 0.f;
    #pragma unroll
    for (int k = 0; k < 4; ++k) {
        int cv = counts[tid + k * 256];
        if (cv > 0) used++;
        float p = (float)cv * invBS;
        ent = fmaf(p, logf(p + 1e-10f), ent);
    }
    sm[tid] = ls; se[tid] = ent; su[tid] = used;
    __syncthreads();
    for (int st = 128; st >= 1; st >>= 1) {
        if (tid < st) { sm[tid] += sm[tid + st]; se[tid] += se[tid + st]; su[tid] += su[tid + st]; }
        __syncthreads();
    }
    if (tid == 0) {
        float m = sm[0] * (1.f / (float)NBIG);
        accums[1] += 0.25f * m + m;                        /* (beta+1)*mse  */
        accums[0] += ((float)su[0] * (1.f / 1024.f)) * 100.f;
        accums[2] += expf(-se[0]);
    }
}

__global__ void final_write_kernel(const float* __restrict__ accums, float* __restrict__ outscal) {
    int t = threadIdx.x;
    if (t < 3) outscal[t] = accums[t] * 0.125f;            /* /= nQ */
}

/* ====================================================================== */
extern "C" void kernel_launch(void* const* d_in, const int* in_sizes, int n_in,
                              void* d_out, int out_size, void* d_ws, size_t ws_size,
                              hipStream_t stream) {
    const float* z  = (const float*)d_in[0];
    const float* cb = (const float*)d_in[1];
    const float* pw = (const float*)d_in[2];
    const float* pb = (const float*)d_in[3];

    float* zhat     = (float*)d_out;
    float* out_scal = zhat + NBIG;
    float* out_idx  = zhat + NBIG + 3;

    char* w = (char*)d_ws;
    half_t* Xd1 = (half_t*)w;  w += (size_t)8192 * NC * 2;
    half_t* Xd2 = (half_t*)w;  w += (size_t)8192 * NC * 2;
    half_t* Xa1 = (half_t*)w;  w += (size_t)NB * 130 * NC * 2;
    half_t* Xa2 = (half_t*)w;  w += (size_t)NB * 130 * NC * 2;
    half_t* Xb1 = (half_t*)w;  w += (size_t)NB * 130 * NC * 2;
    half_t* Xb2 = (half_t*)w;  w += (size_t)NB * 130 * NC * 2;
    half_t* Wt  = (half_t*)w;  w += (size_t)2 * 2 * 4 * 24 * 8192 * 2;   /* 2 convs */
    half_t* CbT = (half_t*)w;  w += (size_t)NQ * 2 * 8 * 8 * 8192 * 2;
    float* pval  = (float*)w;  w += (size_t)8192 * 8 * 4;
    int*   pidx  = (int*)w;    w += (size_t)8192 * 8 * 4;
    int*   idx_i = (int*)w;    w += (size_t)16384 * 4;
    int*   counts= (int*)w;    w += (size_t)NQ * NV * 4;
    float* cnorm = (float*)w;  w += (size_t)NQ * NV * 4;
    float* lpart = (float*)w;  w += (size_t)256 * 4;
    float* accums= (float*)w;  w += 256;

    init_kernel<<<2048, 256, 0, stream>>>(zhat, counts, accums);
    padzero_kernel<<<dim3(64, 2), 512, 0, stream>>>(Xb1, Xb2);
    cnorm_kernel<<<(NQ * NV) / 4, 256, 0, stream>>>(cb, cnorm);
    cbprep_kernel<<<16384, 256, 0, stream>>>(cb, CbT);

    const size_t WT_CONV = (size_t)2 * 4 * 24 * 8192;   /* halves per conv */
    int offq = 0;
    for (int q = 0; q < NQ; ++q) {
        int s = 1 << q;
        int R = NB * s;
        const float* cbq = cb + (size_t)q * NV * NC;
        const float* wq  = pw + (size_t)q * 2 * NC * NC * 3;
        const float* bq0 = pb + (size_t)q * 2 * NC;
        const float* bq1 = bq0 + NC;

        downsample_split_kernel<<<dim3(64, 8), 256, 0, stream>>>(z, zhat, Xd1, Xd2, s, q);
        quant_mfma_kernel<<<dim3(R / 64, 8), 256, 0, stream>>>(
            CbT + (size_t)q * 2 * 8 * 8 * 8192, Xd1, Xd2, cnorm + q * NV, pval, pidx);
        argmin_final_kernel<<<(R + 255) / 256, 256, 0, stream>>>(pval, pidx, idx_i,
                                                                 counts + q * NV, out_idx, R, s, q, offq);
        upsample_split_kernel<<<dim3(64, 130), 512, 0, stream>>>(cbq, idx_i, Xa1, Xa2, s);
        wprep_kernel<<<dim3(3072, 2), 256, 0, stream>>>(wq, Wt);
        conv_mfma_kernel<0><<<dim3(64, 4), 512, 0, stream>>>(
            Wt, Xa1, Xa2, bq0, Xb1, Xb2, nullptr, nullptr, nullptr);
        conv_mfma_kernel<1><<<dim3(64, 4), 512, 0, stream>>>(
            Wt + WT_CONV, Xb1, Xb2, bq1, nullptr, nullptr, zhat, z, lpart);
        scale_final_kernel<<<1, 256, 0, stream>>>(lpart, counts + q * NV, accums, 1.f / (float)(NB * s));
        offq += s;
    }
    final_write_kernel<<<1, 64, 0, stream>>>(accums, out_scal);
}